// Round 1
// baseline (832.646 us; speedup 1.0000x reference)
//
#include <hip/hip_runtime.h>
#include <math.h>

// B=16, C=128, H=128, W=128, MODES=16, RANK=8
// ws layout (float offsets):
//   tab  @ 0      : 6 tables [128][16]: cF,sF (x 1/128), cH,sH, cI2,sI2 (x c_n/128)
//   xtop @ 16384  : (b, i, mn, {re,im})  16*128*256*2 = 1,048,576 floats
//   z    @ 1064960: (b, r, {re,im})      16*8*2 = 256 floats
//   otop @ 1065216: (b, o, mn, {re,im})  1,048,576 floats
#define TAB_OFF 0
#define XTOP_OFF 16384
#define Z_OFF (16384 + 1048576)
#define OTOP_OFF (Z_OFF + 256)

__global__ __launch_bounds__(256) void k_tab(float* __restrict__ tab) {
  int idx = blockIdx.x * 256 + threadIdx.x;
  if (idx >= 12288) return;
  int which = idx >> 11, rem = idx & 2047;
  int a = rem >> 4, j = rem & 15;
  int p = (a * j) & 127;  // exact phase reduction
  float ang = (float)p * (float)(3.14159265358979323846 / 64.0);
  float cv = cosf(ang), sv = sinf(ang);
  float v;
  if (which == 0)      v = cv * (1.f / 128.f);
  else if (which == 1) v = sv * (1.f / 128.f);
  else if (which == 2) v = cv;
  else if (which == 3) v = sv;
  else {
    float cn = (j == 0) ? 1.f : 2.f;
    if (which == 4) v = cn * cv * (1.f / 128.f);
    else            v = cn * sv * (1.f / 128.f);
  }
  tab[idx] = v;
}

// Forward truncated DFT: per (b,c) image -> X[16][16] complex, written (b,i,mn,{re,im})
__global__ __launch_bounds__(256) void k_fwd(const float* __restrict__ x,
                                             const float* __restrict__ tab,
                                             float* __restrict__ xtop) {
  __shared__ float xs[64 * 129];     // half-image, padded rows
  __shared__ float ars[128 * 16];
  __shared__ float ais[128 * 16];
  const int c = blockIdx.x, b = blockIdx.y;
  const int t = threadIdx.x;
  const float* img = x + (((size_t)(b * 128 + c)) << 14);
  const int hl = t >> 2, wq = t & 3;

  for (int half = 0; half < 2; ++half) {
    __syncthreads();
    #pragma unroll
    for (int it = 0; it < 32; ++it) {
      int flat = it * 256 + t;
      int h = flat >> 7, w = flat & 127;
      xs[h * 129 + w] = img[half * 8192 + flat];
    }
    __syncthreads();
    // F1: A[h,n] = sum_w x[h,w] e^{-2pi i n w/128}, partial over w-quarter
    float ar[16], ai[16];
    #pragma unroll
    for (int n = 0; n < 16; ++n) { ar[n] = 0.f; ai[n] = 0.f; }
    const float* xrow = xs + hl * 129 + wq * 32;
    for (int k = 0; k < 32; ++k) {
      int w = wq * 32 + k;
      float xv = xrow[k];
      float cc[16], ss[16];
      #pragma unroll
      for (int q = 0; q < 4; ++q) {
        *(float4*)&cc[q * 4] = *(const float4*)(tab + w * 16 + q * 4);
        *(float4*)&ss[q * 4] = *(const float4*)(tab + 2048 + w * 16 + q * 4);
      }
      #pragma unroll
      for (int n = 0; n < 16; ++n) { ar[n] += xv * cc[n]; ai[n] -= xv * ss[n]; }
    }
    int hg = half * 64 + hl;
    if (wq == 0) {
      #pragma unroll
      for (int n = 0; n < 16; ++n) { ars[hg * 16 + n] = ar[n]; ais[hg * 16 + n] = ai[n]; }
    }
    __syncthreads();
    if (wq == 1) {
      #pragma unroll
      for (int n = 0; n < 16; ++n) { ars[hg * 16 + n] += ar[n]; ais[hg * 16 + n] += ai[n]; }
    }
    __syncthreads();
    if (wq == 2) {
      #pragma unroll
      for (int n = 0; n < 16; ++n) { ars[hg * 16 + n] += ar[n]; ais[hg * 16 + n] += ai[n]; }
    }
    __syncthreads();
    if (wq == 3) {
      #pragma unroll
      for (int n = 0; n < 16; ++n) { ars[hg * 16 + n] += ar[n]; ais[hg * 16 + n] += ai[n]; }
    }
    __syncthreads();
  }
  // F2: X[m,n] = sum_h A[h,n] e^{-2pi i m h/128}
  const int m = t >> 4, n = t & 15;
  float xr = 0.f, xi = 0.f;
  #pragma unroll 8
  for (int hh = 0; hh < 128; ++hh) {
    float arv = ars[hh * 16 + n], aiv = ais[hh * 16 + n];
    float ch = tab[4096 + hh * 16 + m], sh = tab[6144 + hh * 16 + m];
    xr += arv * ch + aiv * sh;
    xi += aiv * ch - arv * sh;
  }
  size_t off = (((size_t)(b * 128 + c)) * 256 + (size_t)t) * 2;
  xtop[off] = xr; xtop[off + 1] = xi;
}

// z[b,r] = sum_{i,mn} x_top[b,i,mn] * conj(V)[i,r,mn]
__global__ __launch_bounds__(256) void k_z(const float* __restrict__ xtop,
                                           const float* __restrict__ vre,
                                           const float* __restrict__ vim,
                                           float* __restrict__ zout) {
  int b = blockIdx.x, t = threadIdx.x;
  float zr[8], zi[8];
  #pragma unroll
  for (int r = 0; r < 8; ++r) { zr[r] = 0.f; zi[r] = 0.f; }
  const float* xb = xtop + ((size_t)b * 128) * 512;
  for (int i = 0; i < 128; ++i) {
    float xr = xb[i * 512 + t * 2], xi = xb[i * 512 + t * 2 + 1];
    #pragma unroll
    for (int r = 0; r < 8; ++r) {
      float vr = vre[(size_t)(i * 8 + r) * 256 + t];
      float vi = vim[(size_t)(i * 8 + r) * 256 + t];
      zr[r] += xr * vr + xi * vi;
      zi[r] += xi * vr - xr * vi;
    }
  }
  #pragma unroll
  for (int r = 0; r < 8; ++r)
    for (int off = 32; off > 0; off >>= 1) {
      zr[r] += __shfl_down(zr[r], off);
      zi[r] += __shfl_down(zi[r], off);
    }
  __shared__ float red[4][16];
  int wid = t >> 6, lane = t & 63;
  if (lane == 0) {
    #pragma unroll
    for (int r = 0; r < 8; ++r) { red[wid][r * 2] = zr[r]; red[wid][r * 2 + 1] = zi[r]; }
  }
  __syncthreads();
  if (t < 16) zout[b * 16 + t] = red[0][t] + red[1][t] + red[2][t] + red[3][t];
}

// out_top[b,o,mn] = sum_i D[o,i,mn]*x_top[b,i,mn] + sum_r U[o,r,mn]*z[b,r]
__global__ __launch_bounds__(256) void k_mix(const float* __restrict__ xtop,
                                             const float* __restrict__ wre,
                                             const float* __restrict__ wim,
                                             const float* __restrict__ ure,
                                             const float* __restrict__ uim,
                                             const float* __restrict__ z,
                                             float* __restrict__ otop) {
  int o0 = blockIdx.x * 4, b0 = blockIdx.y * 2, t = threadIdx.x;
  float ar[2][4], ai[2][4];
  #pragma unroll
  for (int bb = 0; bb < 2; ++bb)
    #pragma unroll
    for (int oo = 0; oo < 4; ++oo) { ar[bb][oo] = 0.f; ai[bb][oo] = 0.f; }
  const float* x0 = xtop + ((size_t)(b0 * 128)) * 512;
  const float* x1 = x0 + 128 * 512;
  for (int i = 0; i < 128; ++i) {
    float x0r = x0[i * 512 + t * 2], x0i = x0[i * 512 + t * 2 + 1];
    float x1r = x1[i * 512 + t * 2], x1i = x1[i * 512 + t * 2 + 1];
    #pragma unroll
    for (int oo = 0; oo < 4; ++oo) {
      size_t di = (size_t)((o0 + oo) * 128 + i) * 256 + t;
      float dr = wre[di], dj = wim[di];
      ar[0][oo] += dr * x0r - dj * x0i; ai[0][oo] += dr * x0i + dj * x0r;
      ar[1][oo] += dr * x1r - dj * x1i; ai[1][oo] += dr * x1i + dj * x1r;
    }
  }
  float zr[2][8], zi[2][8];
  #pragma unroll
  for (int bb = 0; bb < 2; ++bb)
    #pragma unroll
    for (int r = 0; r < 8; ++r) {
      zr[bb][r] = z[(b0 + bb) * 16 + r * 2];
      zi[bb][r] = z[(b0 + bb) * 16 + r * 2 + 1];
    }
  #pragma unroll
  for (int oo = 0; oo < 4; ++oo)
    #pragma unroll
    for (int r = 0; r < 8; ++r) {
      float urv = ure[(size_t)((o0 + oo) * 8 + r) * 256 + t];
      float uiv = uim[(size_t)((o0 + oo) * 8 + r) * 256 + t];
      #pragma unroll
      for (int bb = 0; bb < 2; ++bb) {
        ar[bb][oo] += urv * zr[bb][r] - uiv * zi[bb][r];
        ai[bb][oo] += urv * zi[bb][r] + uiv * zr[bb][r];
      }
    }
  #pragma unroll
  for (int bb = 0; bb < 2; ++bb)
    #pragma unroll
    for (int oo = 0; oo < 4; ++oo) {
      size_t oi = ((size_t)((b0 + bb) * 128 + o0 + oo) * 256 + (size_t)t) * 2;
      otop[oi] = ar[bb][oo]; otop[oi + 1] = ai[bb][oo];
    }
}

// inverse truncated DFT: per (b,o), writes spectral part to out
__global__ __launch_bounds__(256) void k_inv(const float* __restrict__ otop,
                                             const float* __restrict__ tab,
                                             float* __restrict__ out) {
  __shared__ float Xr[256], Xi[256];
  __shared__ float Yr[128 * 16], Yi[128 * 16];
  const int o = blockIdx.x, b = blockIdx.y;
  const int t = threadIdx.x;
  const float* src = otop + ((size_t)((b * 128 + o) * 256)) * 2;
  Xr[t] = src[t * 2]; Xi[t] = src[t * 2 + 1];
  __syncthreads();
  // I1: Y[h,n] = sum_m X[m,n] e^{+2pi i m h/128}
  {
    int h = t >> 1, nh = (t & 1) * 8;
    float yr[8], yi[8];
    #pragma unroll
    for (int j = 0; j < 8; ++j) { yr[j] = 0.f; yi[j] = 0.f; }
    #pragma unroll
    for (int m = 0; m < 16; ++m) {
      float ch = tab[4096 + h * 16 + m], sh = tab[6144 + h * 16 + m];
      #pragma unroll
      for (int j = 0; j < 8; ++j) {
        float xrv = Xr[m * 16 + nh + j], xiv = Xi[m * 16 + nh + j];
        yr[j] += xrv * ch - xiv * sh;
        yi[j] += xrv * sh + xiv * ch;
      }
    }
    #pragma unroll
    for (int j = 0; j < 8; ++j) { Yr[h * 16 + nh + j] = yr[j]; Yi[h * 16 + nh + j] = yi[j]; }
  }
  __syncthreads();
  // I2: out[h,w] = sum_n cI2[w,n]*ReY - sI2[w,n]*ImY   (c_n and 1/128 folded in tables)
  {
    int w64 = t & 63, wq = t >> 6;
    int w0 = w64, w1 = w64 + 64, h0 = wq * 32;
    float cw0[16], sw0[16], cw1[16], sw1[16];
    #pragma unroll
    for (int q = 0; q < 4; ++q) {
      *(float4*)&cw0[q * 4] = *(const float4*)(tab + 8192 + w0 * 16 + q * 4);
      *(float4*)&sw0[q * 4] = *(const float4*)(tab + 10240 + w0 * 16 + q * 4);
      *(float4*)&cw1[q * 4] = *(const float4*)(tab + 8192 + w1 * 16 + q * 4);
      *(float4*)&sw1[q * 4] = *(const float4*)(tab + 10240 + w1 * 16 + q * 4);
    }
    size_t base = ((size_t)(b * 128 + o)) << 14;
    for (int hh = h0; hh < h0 + 32; ++hh) {
      float a0 = 0.f, a1 = 0.f;
      #pragma unroll
      for (int n = 0; n < 16; ++n) {
        float yrv = Yr[hh * 16 + n], yiv = Yi[hh * 16 + n];
        a0 += yrv * cw0[n] - yiv * sw0[n];
        a1 += yrv * cw1[n] - yiv * sw1[n];
      }
      out[base + ((size_t)hh << 7) + w0] = a0;
      out[base + ((size_t)hh << 7) + w1] = a1;
    }
  }
}

// skip GEMM + add spectral + activation, in place on out
__global__ __launch_bounds__(256) void k_skip(const float* __restrict__ x,
                                              const float* __restrict__ sw,
                                              float* __restrict__ out) {
  __shared__ float Wt[128 * 68];   // [k][o], padded
  __shared__ float xsh[16 * 256];  // [kk][hw]
  const int hw0 = blockIdx.x * 256, o0 = blockIdx.y * 64, b = blockIdx.z;
  const int t = threadIdx.x;
  #pragma unroll
  for (int it = 0; it < 32; ++it) {
    int flat = it * 256 + t;
    int oo = flat >> 7, cc = flat & 127;
    Wt[cc * 68 + oo] = sw[(o0 + oo) * 128 + cc];
  }
  const int hwl = t & 63, og = t >> 6;
  float acc[16][4];
  #pragma unroll
  for (int oi = 0; oi < 16; ++oi)
    #pragma unroll
    for (int j = 0; j < 4; ++j) acc[oi][j] = 0.f;
  const float* xb = x + (((size_t)b) << 21) + hw0;
  for (int kc = 0; kc < 8; ++kc) {
    __syncthreads();
    #pragma unroll
    for (int it = 0; it < 16; ++it) {
      int flat = it * 256 + t;
      int kk = flat >> 8, pos = flat & 255;
      xsh[kk * 256 + pos] = xb[((size_t)(kc * 16 + kk) << 14) + pos];
    }
    __syncthreads();
    #pragma unroll 4
    for (int kk = 0; kk < 16; ++kk) {
      int k = kc * 16 + kk;
      float wv[16];
      #pragma unroll
      for (int q = 0; q < 4; ++q)
        *(float4*)&wv[q * 4] = *(const float4*)&Wt[k * 68 + og * 16 + q * 4];
      float xv0 = xsh[kk * 256 + hwl];
      float xv1 = xsh[kk * 256 + hwl + 64];
      float xv2 = xsh[kk * 256 + hwl + 128];
      float xv3 = xsh[kk * 256 + hwl + 192];
      #pragma unroll
      for (int oi = 0; oi < 16; ++oi) {
        acc[oi][0] += wv[oi] * xv0;
        acc[oi][1] += wv[oi] * xv1;
        acc[oi][2] += wv[oi] * xv2;
        acc[oi][3] += wv[oi] * xv3;
      }
    }
  }
  #pragma unroll
  for (int oi = 0; oi < 16; ++oi) {
    int o = o0 + og * 16 + oi;
    size_t rowbase = (((size_t)(b * 128 + o)) << 14) + hw0;
    #pragma unroll
    for (int j = 0; j < 4; ++j) {
      size_t idx = rowbase + hwl + 64 * j;
      float v = acc[oi][j] + out[idx];
      out[idx] = v * __expf(-v * v);
    }
  }
}

extern "C" void kernel_launch(void* const* d_in, const int* in_sizes, int n_in,
                              void* d_out, int out_size, void* d_ws, size_t ws_size,
                              hipStream_t stream) {
  const float* x  = (const float*)d_in[0];
  const float* wr = (const float*)d_in[1];
  const float* wi = (const float*)d_in[2];
  const float* ur = (const float*)d_in[3];
  const float* ui = (const float*)d_in[4];
  const float* vr = (const float*)d_in[5];
  const float* vi = (const float*)d_in[6];
  const float* sw = (const float*)d_in[7];
  float* out  = (float*)d_out;
  float* ws   = (float*)d_ws;
  float* tab  = ws + TAB_OFF;
  float* xtop = ws + XTOP_OFF;
  float* z    = ws + Z_OFF;
  float* otop = ws + OTOP_OFF;

  hipLaunchKernelGGL(k_tab, dim3(48), dim3(256), 0, stream, tab);
  hipLaunchKernelGGL(k_fwd, dim3(128, 16), dim3(256), 0, stream, x, tab, xtop);
  hipLaunchKernelGGL(k_z,   dim3(16), dim3(256), 0, stream, xtop, vr, vi, z);
  hipLaunchKernelGGL(k_mix, dim3(32, 8), dim3(256), 0, stream, xtop, wr, wi, ur, ui, z, otop);
  hipLaunchKernelGGL(k_inv, dim3(128, 16), dim3(256), 0, stream, otop, tab, out);
  hipLaunchKernelGGL(k_skip, dim3(64, 2, 16), dim3(256), 0, stream, x, sw, out);
}

// Round 2
// 459.621 us; speedup vs baseline: 1.8116x; 1.8116x over previous
//
#include <hip/hip_runtime.h>
#include <math.h>

// B=16, C=128, H=128, W=128, MODES=16, RANK=8
// ws layout (float offsets):
//   tab  @ 0      : 8 tables of 2048 floats each (see below)
//   xtop @ 16384  : (b, i, mn, {re,im})  16*128*256*2 = 1,048,576 floats
//   z    @ 1064960: (b, r, {re,im})      16*8*2 = 256 floats
//   otop @ 1065216: (b, o, mn, {re,im})  1,048,576 floats
#define TAB_OFF 0
#define XTOP_OFF 16384
#define Z_OFF (16384 + 1048576)
#define OTOP_OFF (Z_OFF + 256)

// table float offsets (each table [2048]):
//     0  T1C  [w][n]   cos(2pi wn/128)/128
//  2048  T1NS [w][n]  -sin(2pi wn/128)/128
//  4096  T2C  [h][m]   cos(2pi hm/128)
//  6144  T2S  [h][m]   sin(2pi hm/128)
//  8192  T2CT [m][h]   cos(2pi hm/128)
// 10240  T2ST [m][h]   sin(2pi hm/128)
// 12288  I2C  [w][n]   c_n*cos(2pi wn/128)/128   (c_0=1, else 2)
// 14336  I2NS [w][n]  -c_n*sin(2pi wn/128)/128

__global__ __launch_bounds__(256) void k_tab(float* __restrict__ tab) {
  int idx = blockIdx.x * 256 + threadIdx.x;
  if (idx >= 16384) return;
  int which = idx >> 11, rem = idx & 2047;
  int a, j;
  if (which == 4 || which == 5) { a = rem & 127; j = rem >> 7; }  // [m][h]
  else { a = rem >> 4; j = rem & 15; }
  int p = (a * j) & 127;  // exact phase reduction
  float ang = (float)p * (float)(3.14159265358979323846 / 64.0);
  float cv = cosf(ang), sv = sinf(ang);
  float v;
  switch (which) {
    case 0: v = cv * (1.f / 128.f); break;
    case 1: v = -sv * (1.f / 128.f); break;
    case 2: v = cv; break;
    case 3: v = sv; break;
    case 4: v = cv; break;
    case 5: v = sv; break;
    case 6: v = ((rem & 15) == 0 ? 1.f : 2.f) * cv * (1.f / 128.f); break;
    default: v = ((rem & 15) == 0 ? 1.f : 2.f) * (-sv) * (1.f / 128.f); break;
  }
  tab[idx] = v;
}

// Forward truncated DFT. Block = one (b,c) image, 128 threads (2 waves).
// Lane owns row h=t. F1: A[h][n] = sum_w x[h][w] e^{-2pi i n w/128}/128 in regs,
// tables via wave-uniform s_load. F2 through small LDS transpose.
__global__ __launch_bounds__(128) void k_fwd(const float* __restrict__ x,
                                             const float* __restrict__ tab,
                                             float* __restrict__ xtop) {
  __shared__ float Ar[16][132];  // [n][h], 528B row stride (16B-aligned)
  __shared__ float Ai[16][132];
  const int c = blockIdx.x, b = blockIdx.y;
  const int t = threadIdx.x;  // h = t
  const float* row = x + (((size_t)(b * 128 + c)) << 14) + (size_t)t * 128;

  float ar[16], ai[16];
  #pragma unroll
  for (int n = 0; n < 16; ++n) { ar[n] = 0.f; ai[n] = 0.f; }

  for (int w0 = 0; w0 < 128; w0 += 16) {
    float xv[16];
    #pragma unroll
    for (int q = 0; q < 4; ++q)
      *(float4*)&xv[q * 4] = *(const float4*)(row + w0 + q * 4);
    #pragma unroll
    for (int w = 0; w < 16; ++w) {
      const float* tc = tab + (w0 + w) * 16;          // uniform -> s_load
      const float* ts = tab + 2048 + (w0 + w) * 16;   // uniform -> s_load
      #pragma unroll
      for (int n = 0; n < 16; ++n) {
        ar[n] += xv[w] * tc[n];
        ai[n] += xv[w] * ts[n];
      }
    }
  }
  #pragma unroll
  for (int n = 0; n < 16; ++n) { Ar[n][t] = ar[n]; Ai[n][t] = ai[n]; }
  __syncthreads();

  // F2: X[m][n] = sum_h A[h][n] e^{-2pi i m h/128}; thread does m0=t>>4 and m0+8, n=t&15
  const int n = t & 15, m0 = t >> 4;
  const float* tc0 = tab + 8192 + m0 * 128;   // T2CT[m0][h]
  const float* ts0 = tab + 10240 + m0 * 128;
  const float* tc1 = tc0 + 1024;              // m0+8
  const float* ts1 = ts0 + 1024;
  float xr0 = 0.f, xi0 = 0.f, xr1 = 0.f, xi1 = 0.f;
  for (int h4 = 0; h4 < 128; h4 += 4) {
    float arv[4], aiv[4], cc0[4], ss0[4], cc1[4], ss1[4];
    *(float4*)arv = *(const float4*)&Ar[n][h4];
    *(float4*)aiv = *(const float4*)&Ai[n][h4];
    *(float4*)cc0 = *(const float4*)(tc0 + h4);
    *(float4*)ss0 = *(const float4*)(ts0 + h4);
    *(float4*)cc1 = *(const float4*)(tc1 + h4);
    *(float4*)ss1 = *(const float4*)(ts1 + h4);
    #pragma unroll
    for (int j = 0; j < 4; ++j) {
      xr0 += arv[j] * cc0[j] + aiv[j] * ss0[j];
      xi0 += aiv[j] * cc0[j] - arv[j] * ss0[j];
      xr1 += arv[j] * cc1[j] + aiv[j] * ss1[j];
      xi1 += aiv[j] * cc1[j] - arv[j] * ss1[j];
    }
  }
  size_t base = ((size_t)(b * 128 + c)) * 512 + (size_t)t * 2;
  xtop[base] = xr0; xtop[base + 1] = xi0;
  xtop[base + 256] = xr1; xtop[base + 257] = xi1;
}

// z[b,r] = sum_{i,mn} x_top[b,i,mn] * conj(V)[i,r,mn]
__global__ __launch_bounds__(256) void k_z(const float* __restrict__ xtop,
                                           const float* __restrict__ vre,
                                           const float* __restrict__ vim,
                                           float* __restrict__ zout) {
  int b = blockIdx.x, t = threadIdx.x;
  float zr[8], zi[8];
  #pragma unroll
  for (int r = 0; r < 8; ++r) { zr[r] = 0.f; zi[r] = 0.f; }
  const float* xb = xtop + ((size_t)b * 128) * 512;
  for (int i = 0; i < 128; ++i) {
    float xr = xb[i * 512 + t * 2], xi = xb[i * 512 + t * 2 + 1];
    #pragma unroll
    for (int r = 0; r < 8; ++r) {
      float vr = vre[(size_t)(i * 8 + r) * 256 + t];
      float vi = vim[(size_t)(i * 8 + r) * 256 + t];
      zr[r] += xr * vr + xi * vi;
      zi[r] += xi * vr - xr * vi;
    }
  }
  #pragma unroll
  for (int r = 0; r < 8; ++r)
    for (int off = 32; off > 0; off >>= 1) {
      zr[r] += __shfl_down(zr[r], off);
      zi[r] += __shfl_down(zi[r], off);
    }
  __shared__ float red[4][16];
  int wid = t >> 6, lane = t & 63;
  if (lane == 0) {
    #pragma unroll
    for (int r = 0; r < 8; ++r) { red[wid][r * 2] = zr[r]; red[wid][r * 2 + 1] = zi[r]; }
  }
  __syncthreads();
  if (t < 16) zout[b * 16 + t] = red[0][t] + red[1][t] + red[2][t] + red[3][t];
}

// out_top[b,o,mn] = sum_i D[o,i,mn]*x_top[b,i,mn] + sum_r U[o,r,mn]*z[b,r]
__global__ __launch_bounds__(256) void k_mix(const float* __restrict__ xtop,
                                             const float* __restrict__ wre,
                                             const float* __restrict__ wim,
                                             const float* __restrict__ ure,
                                             const float* __restrict__ uim,
                                             const float* __restrict__ z,
                                             float* __restrict__ otop) {
  int o0 = blockIdx.x * 4, b0 = blockIdx.y * 2, t = threadIdx.x;
  float ar[2][4], ai[2][4];
  #pragma unroll
  for (int bb = 0; bb < 2; ++bb)
    #pragma unroll
    for (int oo = 0; oo < 4; ++oo) { ar[bb][oo] = 0.f; ai[bb][oo] = 0.f; }
  const float* x0 = xtop + ((size_t)(b0 * 128)) * 512;
  const float* x1 = x0 + 128 * 512;
  for (int i = 0; i < 128; ++i) {
    float x0r = x0[i * 512 + t * 2], x0i = x0[i * 512 + t * 2 + 1];
    float x1r = x1[i * 512 + t * 2], x1i = x1[i * 512 + t * 2 + 1];
    #pragma unroll
    for (int oo = 0; oo < 4; ++oo) {
      size_t di = (size_t)((o0 + oo) * 128 + i) * 256 + t;
      float dr = wre[di], dj = wim[di];
      ar[0][oo] += dr * x0r - dj * x0i; ai[0][oo] += dr * x0i + dj * x0r;
      ar[1][oo] += dr * x1r - dj * x1i; ai[1][oo] += dr * x1i + dj * x1r;
    }
  }
  float zr[2][8], zi[2][8];
  #pragma unroll
  for (int bb = 0; bb < 2; ++bb)
    #pragma unroll
    for (int r = 0; r < 8; ++r) {
      zr[bb][r] = z[(b0 + bb) * 16 + r * 2];
      zi[bb][r] = z[(b0 + bb) * 16 + r * 2 + 1];
    }
  #pragma unroll
  for (int oo = 0; oo < 4; ++oo)
    #pragma unroll
    for (int r = 0; r < 8; ++r) {
      float urv = ure[(size_t)((o0 + oo) * 8 + r) * 256 + t];
      float uiv = uim[(size_t)((o0 + oo) * 8 + r) * 256 + t];
      #pragma unroll
      for (int bb = 0; bb < 2; ++bb) {
        ar[bb][oo] += urv * zr[bb][r] - uiv * zi[bb][r];
        ai[bb][oo] += urv * zi[bb][r] + uiv * zr[bb][r];
      }
    }
  #pragma unroll
  for (int bb = 0; bb < 2; ++bb)
    #pragma unroll
    for (int oo = 0; oo < 4; ++oo) {
      size_t oi = ((size_t)((b0 + bb) * 128 + o0 + oo) * 256 + (size_t)t) * 2;
      otop[oi] = ar[bb][oo]; otop[oi + 1] = ai[bb][oo];
    }
}

// Inverse truncated DFT. Block = one (b,o) image, 128 threads (2 waves).
// Lane owns row h=t; Y[h][n] in regs; I2 tables via wave-uniform s_load;
// output staged through a small LDS tile for coalesced stores.
__global__ __launch_bounds__(128) void k_inv(const float* __restrict__ otop,
                                             const float* __restrict__ tab,
                                             float* __restrict__ out) {
  __shared__ float Xs[512];
  __shared__ float tile[128 * 18];  // [r][16w], pad 18
  const int o = blockIdx.x, b = blockIdx.y;
  const int t = threadIdx.x;  // h = t
  const float* src = otop + (((size_t)(b * 128 + o)) << 9);
  *(float4*)&Xs[t * 4] = *(const float4*)(src + t * 4);
  // per-lane table row T2[h][m]
  float c2[16], s2[16];
  #pragma unroll
  for (int q = 0; q < 4; ++q) {
    *(float4*)&c2[q * 4] = *(const float4*)(tab + 4096 + t * 16 + q * 4);
    *(float4*)&s2[q * 4] = *(const float4*)(tab + 6144 + t * 16 + q * 4);
  }
  __syncthreads();
  // I1: Y[n] = sum_m X[m][n] e^{+2pi i m h/128}
  float yr[16], yi[16];
  #pragma unroll
  for (int nn = 0; nn < 16; ++nn) { yr[nn] = 0.f; yi[nn] = 0.f; }
  #pragma unroll
  for (int m = 0; m < 16; ++m) {
    #pragma unroll
    for (int nn = 0; nn < 16; ++nn) {
      float xr = Xs[m * 32 + nn * 2], xi = Xs[m * 32 + nn * 2 + 1];
      yr[nn] += xr * c2[m] - xi * s2[m];
      yi[nn] += xr * s2[m] + xi * c2[m];
    }
  }
  // I2: out[h][w] = sum_n yr*I2C[w][n] + yi*I2NS[w][n]
  size_t obase = ((size_t)(b * 128 + o)) << 14;
  for (int wb = 0; wb < 8; ++wb) {
    if (wb) __syncthreads();
    #pragma unroll
    for (int w = 0; w < 16; ++w) {
      const float* ic = tab + 12288 + (wb * 16 + w) * 16;  // uniform -> s_load
      const float* is = tab + 14336 + (wb * 16 + w) * 16;
      float a = 0.f;
      #pragma unroll
      for (int nn = 0; nn < 16; ++nn) a += yr[nn] * ic[nn] + yi[nn] * is[nn];
      tile[t * 18 + w] = a;
    }
    __syncthreads();
    #pragma unroll
    for (int g = 0; g < 16; ++g) {
      int flat = g * 128 + t;
      int r = flat >> 4, w = flat & 15;
      out[obase + (size_t)r * 128 + wb * 16 + w] = tile[r * 18 + w];
    }
  }
}

// skip GEMM + add spectral + activation, in place on out
__global__ __launch_bounds__(256) void k_skip(const float* __restrict__ x,
                                              const float* __restrict__ sw,
                                              float* __restrict__ out) {
  __shared__ float Wt[128 * 68];   // [k][o], padded
  __shared__ float xsh[16 * 256];  // [kk][hw]
  const int hw0 = blockIdx.x * 256, o0 = blockIdx.y * 64, b = blockIdx.z;
  const int t = threadIdx.x;
  #pragma unroll
  for (int it = 0; it < 32; ++it) {
    int flat = it * 256 + t;
    int oo = flat >> 7, cc = flat & 127;
    Wt[cc * 68 + oo] = sw[(o0 + oo) * 128 + cc];
  }
  const int hwl = t & 63, og = t >> 6;
  float acc[16][4];
  #pragma unroll
  for (int oi = 0; oi < 16; ++oi)
    #pragma unroll
    for (int j = 0; j < 4; ++j) acc[oi][j] = 0.f;
  const float* xb = x + (((size_t)b) << 21) + hw0;
  for (int kc = 0; kc < 8; ++kc) {
    __syncthreads();
    #pragma unroll
    for (int it = 0; it < 16; ++it) {
      int flat = it * 256 + t;
      int kk = flat >> 8, pos = flat & 255;
      xsh[kk * 256 + pos] = xb[((size_t)(kc * 16 + kk) << 14) + pos];
    }
    __syncthreads();
    #pragma unroll 4
    for (int kk = 0; kk < 16; ++kk) {
      int k = kc * 16 + kk;
      float wv[16];
      #pragma unroll
      for (int q = 0; q < 4; ++q)
        *(float4*)&wv[q * 4] = *(const float4*)&Wt[k * 68 + og * 16 + q * 4];
      float xv0 = xsh[kk * 256 + hwl];
      float xv1 = xsh[kk * 256 + hwl + 64];
      float xv2 = xsh[kk * 256 + hwl + 128];
      float xv3 = xsh[kk * 256 + hwl + 192];
      #pragma unroll
      for (int oi = 0; oi < 16; ++oi) {
        acc[oi][0] += wv[oi] * xv0;
        acc[oi][1] += wv[oi] * xv1;
        acc[oi][2] += wv[oi] * xv2;
        acc[oi][3] += wv[oi] * xv3;
      }
    }
  }
  #pragma unroll
  for (int oi = 0; oi < 16; ++oi) {
    int o = o0 + og * 16 + oi;
    size_t rowbase = (((size_t)(b * 128 + o)) << 14) + hw0;
    #pragma unroll
    for (int j = 0; j < 4; ++j) {
      size_t idx = rowbase + hwl + 64 * j;
      float v = acc[oi][j] + out[idx];
      out[idx] = v * __expf(-v * v);
    }
  }
}

extern "C" void kernel_launch(void* const* d_in, const int* in_sizes, int n_in,
                              void* d_out, int out_size, void* d_ws, size_t ws_size,
                              hipStream_t stream) {
  const float* x  = (const float*)d_in[0];
  const float* wr = (const float*)d_in[1];
  const float* wi = (const float*)d_in[2];
  const float* ur = (const float*)d_in[3];
  const float* ui = (const float*)d_in[4];
  const float* vr = (const float*)d_in[5];
  const float* vi = (const float*)d_in[6];
  const float* sw = (const float*)d_in[7];
  float* out  = (float*)d_out;
  float* ws   = (float*)d_ws;
  float* tab  = ws + TAB_OFF;
  float* xtop = ws + XTOP_OFF;
  float* z    = ws + Z_OFF;
  float* otop = ws + OTOP_OFF;

  hipLaunchKernelGGL(k_tab, dim3(64), dim3(256), 0, stream, tab);
  hipLaunchKernelGGL(k_fwd, dim3(128, 16), dim3(128), 0, stream, x, tab, xtop);
  hipLaunchKernelGGL(k_z,   dim3(16), dim3(256), 0, stream, xtop, vr, vi, z);
  hipLaunchKernelGGL(k_mix, dim3(32, 8), dim3(256), 0, stream, xtop, wr, wi, ur, ui, z, otop);
  hipLaunchKernelGGL(k_inv, dim3(128, 16), dim3(128), 0, stream, otop, tab, out);
  hipLaunchKernelGGL(k_skip, dim3(64, 2, 16), dim3(256), 0, stream, x, sw, out);
}

// Round 3
// 287.738 us; speedup vs baseline: 2.8938x; 1.5974x over previous
//
#include <hip/hip_runtime.h>
#include <math.h>

// B=16, C=128, H=128, W=128, MODES=16, RANK=8
// ws layout (float offsets):
//   tab  @ 0      : 8 tables of 2048 floats each (see below)
//   xtop @ 16384  : (b, i, mn, {re,im})  16*128*256*2 = 1,048,576 floats
//   z    @ 1064960: (b, r, {re,im})      16*8*2 = 256 floats
//   otop @ 1065216: (b, o, mn, {re,im})  1,048,576 floats
#define TAB_OFF 0
#define XTOP_OFF 16384
#define Z_OFF (16384 + 1048576)
#define OTOP_OFF (Z_OFF + 256)

// table float offsets (each table [2048]):
//     0  T1C  [w][n]   cos(2pi wn/128)/128
//  2048  T1NS [w][n]  -sin(2pi wn/128)/128
//  4096  T2C  [h][m]   cos(2pi hm/128)
//  6144  T2S  [h][m]   sin(2pi hm/128)
//  8192  T2CT [m][h]   cos(2pi hm/128)
// 10240  T2ST [m][h]   sin(2pi hm/128)
// 12288  I2C  [w][n]   c_n*cos(2pi wn/128)/128   (c_0=1, else 2)
// 14336  I2NS [w][n]  -c_n*sin(2pi wn/128)/128

using bf16x8 = __attribute__((ext_vector_type(8))) short;
using s16x4  = __attribute__((ext_vector_type(4))) short;
using f32x16 = __attribute__((ext_vector_type(16))) float;

__device__ inline unsigned short bf_rnd(float v) {
  return (unsigned short)((__float_as_uint(v) + 0x8000u) >> 16);
}
__device__ inline void bf_split(float v, unsigned short& hi, unsigned short& lo) {
  unsigned u = __float_as_uint(v);
  hi = (unsigned short)(u >> 16);
  float r = v - __uint_as_float(u & 0xFFFF0000u);
  lo = (unsigned short)(__float_as_uint(r) >> 16);
}
__device__ inline bf16x8 ldfrag(const unsigned short* p) {
  s16x4 a = *(const s16x4*)p;        // ds_read_b64 (8B aligned)
  s16x4 b = *(const s16x4*)(p + 4);
  bf16x8 r;
  r[0] = a[0]; r[1] = a[1]; r[2] = a[2]; r[3] = a[3];
  r[4] = b[0]; r[5] = b[1]; r[6] = b[2]; r[7] = b[3];
  return r;
}

__global__ __launch_bounds__(256) void k_tab(float* __restrict__ tab) {
  int idx = blockIdx.x * 256 + threadIdx.x;
  if (idx >= 16384) return;
  int which = idx >> 11, rem = idx & 2047;
  int a, j;
  if (which == 4 || which == 5) { a = rem & 127; j = rem >> 7; }  // [m][h]
  else { a = rem >> 4; j = rem & 15; }
  int p = (a * j) & 127;  // exact phase reduction
  float ang = (float)p * (float)(3.14159265358979323846 / 64.0);
  float cv = cosf(ang), sv = sinf(ang);
  float v;
  switch (which) {
    case 0: v = cv * (1.f / 128.f); break;
    case 1: v = -sv * (1.f / 128.f); break;
    case 2: v = cv; break;
    case 3: v = sv; break;
    case 4: v = cv; break;
    case 5: v = sv; break;
    case 6: v = ((rem & 15) == 0 ? 1.f : 2.f) * cv * (1.f / 128.f); break;
    default: v = ((rem & 15) == 0 ? 1.f : 2.f) * (-sv) * (1.f / 128.f); break;
  }
  tab[idx] = v;
}

// Forward truncated DFT. Block = one (b,c) image, 128 threads (2 waves).
__global__ __launch_bounds__(128) void k_fwd(const float* __restrict__ x,
                                             const float* __restrict__ tab,
                                             float* __restrict__ xtop) {
  __shared__ float Ar[16][132];
  __shared__ float Ai[16][132];
  const int c = blockIdx.x, b = blockIdx.y;
  const int t = threadIdx.x;  // h = t
  const float* row = x + (((size_t)(b * 128 + c)) << 14) + (size_t)t * 128;

  float ar[16], ai[16];
  #pragma unroll
  for (int n = 0; n < 16; ++n) { ar[n] = 0.f; ai[n] = 0.f; }

  for (int w0 = 0; w0 < 128; w0 += 16) {
    float xv[16];
    #pragma unroll
    for (int q = 0; q < 4; ++q)
      *(float4*)&xv[q * 4] = *(const float4*)(row + w0 + q * 4);
    #pragma unroll
    for (int w = 0; w < 16; ++w) {
      const float* tc = tab + (w0 + w) * 16;          // uniform -> s_load
      const float* ts = tab + 2048 + (w0 + w) * 16;
      #pragma unroll
      for (int n = 0; n < 16; ++n) {
        ar[n] += xv[w] * tc[n];
        ai[n] += xv[w] * ts[n];
      }
    }
  }
  #pragma unroll
  for (int n = 0; n < 16; ++n) { Ar[n][t] = ar[n]; Ai[n][t] = ai[n]; }
  __syncthreads();

  const int n = t & 15, m0 = t >> 4;
  const float* tc0 = tab + 8192 + m0 * 128;
  const float* ts0 = tab + 10240 + m0 * 128;
  const float* tc1 = tc0 + 1024;
  const float* ts1 = ts0 + 1024;
  float xr0 = 0.f, xi0 = 0.f, xr1 = 0.f, xi1 = 0.f;
  for (int h4 = 0; h4 < 128; h4 += 4) {
    float arv[4], aiv[4], cc0[4], ss0[4], cc1[4], ss1[4];
    *(float4*)arv = *(const float4*)&Ar[n][h4];
    *(float4*)aiv = *(const float4*)&Ai[n][h4];
    *(float4*)cc0 = *(const float4*)(tc0 + h4);
    *(float4*)ss0 = *(const float4*)(ts0 + h4);
    *(float4*)cc1 = *(const float4*)(tc1 + h4);
    *(float4*)ss1 = *(const float4*)(ts1 + h4);
    #pragma unroll
    for (int j = 0; j < 4; ++j) {
      xr0 += arv[j] * cc0[j] + aiv[j] * ss0[j];
      xi0 += aiv[j] * cc0[j] - arv[j] * ss0[j];
      xr1 += arv[j] * cc1[j] + aiv[j] * ss1[j];
      xi1 += aiv[j] * cc1[j] - arv[j] * ss1[j];
    }
  }
  size_t base = ((size_t)(b * 128 + c)) * 512 + (size_t)t * 2;
  xtop[base] = xr0; xtop[base + 1] = xi0;
  xtop[base + 256] = xr1; xtop[base + 257] = xi1;
}

// z[b,r] = sum_{i,mn} x_top[b,i,mn] * conj(V)[i,r,mn]
__global__ __launch_bounds__(256) void k_z(const float* __restrict__ xtop,
                                           const float* __restrict__ vre,
                                           const float* __restrict__ vim,
                                           float* __restrict__ zout) {
  int b = blockIdx.x, t = threadIdx.x;
  float zr[8], zi[8];
  #pragma unroll
  for (int r = 0; r < 8; ++r) { zr[r] = 0.f; zi[r] = 0.f; }
  const float* xb = xtop + ((size_t)b * 128) * 512;
  for (int i = 0; i < 128; ++i) {
    float xr = xb[i * 512 + t * 2], xi = xb[i * 512 + t * 2 + 1];
    #pragma unroll
    for (int r = 0; r < 8; ++r) {
      float vr = vre[(size_t)(i * 8 + r) * 256 + t];
      float vi = vim[(size_t)(i * 8 + r) * 256 + t];
      zr[r] += xr * vr + xi * vi;
      zi[r] += xi * vr - xr * vi;
    }
  }
  #pragma unroll
  for (int r = 0; r < 8; ++r)
    for (int off = 32; off > 0; off >>= 1) {
      zr[r] += __shfl_down(zr[r], off);
      zi[r] += __shfl_down(zi[r], off);
    }
  __shared__ float red[4][16];
  int wid = t >> 6, lane = t & 63;
  if (lane == 0) {
    #pragma unroll
    for (int r = 0; r < 8; ++r) { red[wid][r * 2] = zr[r]; red[wid][r * 2 + 1] = zi[r]; }
  }
  __syncthreads();
  if (t < 16) zout[b * 16 + t] = red[0][t] + red[1][t] + red[2][t] + red[3][t];
}

// out_top[b,o,mn] = sum_i D[o,i,mn]*x_top[b,i,mn] + sum_r U[o,r,mn]*z[b,r]
__global__ __launch_bounds__(256) void k_mix(const float* __restrict__ xtop,
                                             const float* __restrict__ wre,
                                             const float* __restrict__ wim,
                                             const float* __restrict__ ure,
                                             const float* __restrict__ uim,
                                             const float* __restrict__ z,
                                             float* __restrict__ otop) {
  int o0 = blockIdx.x * 4, b0 = blockIdx.y * 2, t = threadIdx.x;
  float ar[2][4], ai[2][4];
  #pragma unroll
  for (int bb = 0; bb < 2; ++bb)
    #pragma unroll
    for (int oo = 0; oo < 4; ++oo) { ar[bb][oo] = 0.f; ai[bb][oo] = 0.f; }
  const float* x0 = xtop + ((size_t)(b0 * 128)) * 512;
  const float* x1 = x0 + 128 * 512;
  for (int i = 0; i < 128; ++i) {
    float x0r = x0[i * 512 + t * 2], x0i = x0[i * 512 + t * 2 + 1];
    float x1r = x1[i * 512 + t * 2], x1i = x1[i * 512 + t * 2 + 1];
    #pragma unroll
    for (int oo = 0; oo < 4; ++oo) {
      size_t di = (size_t)((o0 + oo) * 128 + i) * 256 + t;
      float dr = wre[di], dj = wim[di];
      ar[0][oo] += dr * x0r - dj * x0i; ai[0][oo] += dr * x0i + dj * x0r;
      ar[1][oo] += dr * x1r - dj * x1i; ai[1][oo] += dr * x1i + dj * x1r;
    }
  }
  float zr[2][8], zi[2][8];
  #pragma unroll
  for (int bb = 0; bb < 2; ++bb)
    #pragma unroll
    for (int r = 0; r < 8; ++r) {
      zr[bb][r] = z[(b0 + bb) * 16 + r * 2];
      zi[bb][r] = z[(b0 + bb) * 16 + r * 2 + 1];
    }
  #pragma unroll
  for (int oo = 0; oo < 4; ++oo)
    #pragma unroll
    for (int r = 0; r < 8; ++r) {
      float urv = ure[(size_t)((o0 + oo) * 8 + r) * 256 + t];
      float uiv = uim[(size_t)((o0 + oo) * 8 + r) * 256 + t];
      #pragma unroll
      for (int bb = 0; bb < 2; ++bb) {
        ar[bb][oo] += urv * zr[bb][r] - uiv * zi[bb][r];
        ai[bb][oo] += urv * zi[bb][r] + uiv * zr[bb][r];
      }
    }
  #pragma unroll
  for (int bb = 0; bb < 2; ++bb)
    #pragma unroll
    for (int oo = 0; oo < 4; ++oo) {
      size_t oi = ((size_t)((b0 + bb) * 128 + o0 + oo) * 256 + (size_t)t) * 2;
      otop[oi] = ar[bb][oo]; otop[oi + 1] = ai[bb][oo];
    }
}

// Fused inverse-DFT + skip-GEMM + activation.
// Block = (h, b): output tile [128 o][128 w].
// Skip GEMM via 3-product split-bf16 MFMA (error ~2^-18); spectral I2 via
// plain-bf16 MFMA into the SAME accumulators; I1 (tiny) in fp32 VALU.
// LDS rows padded to 36 shorts (72 B = 18 dwords): b16 writes 2-way,
// ds_read_b64 frag reads conflict-free.
__global__ __launch_bounds__(256) void k_out(const float* __restrict__ x,
                                             const float* __restrict__ sw,
                                             const float* __restrict__ otop,
                                             const float* __restrict__ tab,
                                             float* __restrict__ out) {
  __shared__ unsigned short Ylds[128 * 36];  // [o][k]: k<16 Yr[n], k>=16 Yi[n]
  __shared__ unsigned short Tlds[128 * 36];  // [w][k]: k<16 I2C[w][n], k>=16 I2NS[w][n]
  __shared__ unsigned short Bh[128 * 36], Bl[128 * 36];  // x tile  [w][c_local]
  __shared__ unsigned short Ah[128 * 36], Al[128 * 36];  // sw tile [o][c_local]
  const int h = blockIdx.x, b = blockIdx.y;
  const int t = threadIdx.x;
  const int lane = t & 63, wv = t >> 6;

  // ---- build T' (bf16 I2 tables, concatenated cos|sin per w) ----
  {
    int w = t >> 1, half = t & 1;
    const float* src = tab + (half ? 14336 : 12288) + w * 16;
    #pragma unroll
    for (int q = 0; q < 4; ++q) {
      float4 v = *(const float4*)(src + q * 4);
      int k0 = half * 16 + q * 4;
      Tlds[w * 36 + k0 + 0] = bf_rnd(v.x);
      Tlds[w * 36 + k0 + 1] = bf_rnd(v.y);
      Tlds[w * 36 + k0 + 2] = bf_rnd(v.z);
      Tlds[w * 36 + k0 + 3] = bf_rnd(v.w);
    }
  }
  // ---- I1: Y[o][n] = sum_m X[o][m][n] e^{+2pi i m h/128} (fp32) ----
  {
    int o = t >> 1, nh = (t & 1) * 8;
    float yr[8], yi[8];
    #pragma unroll
    for (int j = 0; j < 8; ++j) { yr[j] = 0.f; yi[j] = 0.f; }
    const float* xb = otop + ((size_t)(b * 128 + o)) * 512 + nh * 2;
    #pragma unroll 4
    for (int m = 0; m < 16; ++m) {
      float cm = tab[4096 + h * 16 + m];   // uniform -> s_load
      float sm = tab[6144 + h * 16 + m];
      float4 q0 = *(const float4*)(xb + m * 32 + 0);
      float4 q1 = *(const float4*)(xb + m * 32 + 4);
      float4 q2 = *(const float4*)(xb + m * 32 + 8);
      float4 q3 = *(const float4*)(xb + m * 32 + 12);
      yr[0] += q0.x * cm - q0.y * sm; yi[0] += q0.x * sm + q0.y * cm;
      yr[1] += q0.z * cm - q0.w * sm; yi[1] += q0.z * sm + q0.w * cm;
      yr[2] += q1.x * cm - q1.y * sm; yi[2] += q1.x * sm + q1.y * cm;
      yr[3] += q1.z * cm - q1.w * sm; yi[3] += q1.z * sm + q1.w * cm;
      yr[4] += q2.x * cm - q2.y * sm; yi[4] += q2.x * sm + q2.y * cm;
      yr[5] += q2.z * cm - q2.w * sm; yi[5] += q2.z * sm + q2.w * cm;
      yr[6] += q3.x * cm - q3.y * sm; yi[6] += q3.x * sm + q3.y * cm;
      yr[7] += q3.z * cm - q3.w * sm; yi[7] += q3.z * sm + q3.w * cm;
    }
    #pragma unroll
    for (int j = 0; j < 8; ++j) {
      Ylds[o * 36 + nh + j] = bf_rnd(yr[j]);
      Ylds[o * 36 + 16 + nh + j] = bf_rnd(yi[j]);
    }
  }
  __syncthreads();

  f32x16 acc[4];
  #pragma unroll
  for (int nt = 0; nt < 4; ++nt)
    #pragma unroll
    for (int e = 0; e < 16; ++e) acc[nt][e] = 0.f;

  // ---- skip GEMM: C[o][w] = sum_c sw[o][c] x[b][c][h][w], K in 4 chunks ----
  for (int kc = 0; kc < 4; ++kc) {
    float xv[16], wv16[16];
    #pragma unroll
    for (int it = 0; it < 16; ++it) {
      int c = kc * 32 + it * 2 + (t >> 7);
      int w = t & 127;
      xv[it] = x[(size_t)(b * 128 + c) * 16384 + (size_t)h * 128 + w];
    }
    #pragma unroll
    for (int it = 0; it < 16; ++it) {
      int idx = it * 256 + t;
      int o = idx >> 5, cl = idx & 31;
      wv16[it] = sw[o * 128 + kc * 32 + cl];
    }
    __syncthreads();  // previous chunk's frag reads complete
    #pragma unroll
    for (int it = 0; it < 16; ++it) {
      int cl = it * 2 + (t >> 7);
      int w = t & 127;
      unsigned short hb, lb;
      bf_split(xv[it], hb, lb);
      Bh[w * 36 + cl] = hb; Bl[w * 36 + cl] = lb;
    }
    #pragma unroll
    for (int it = 0; it < 16; ++it) {
      int idx = it * 256 + t;
      int o = idx >> 5, cl = idx & 31;
      unsigned short hb, lb;
      bf_split(wv16[it], hb, lb);
      Ah[o * 36 + cl] = hb; Al[o * 36 + cl] = lb;
    }
    __syncthreads();
    #pragma unroll
    for (int ks = 0; ks < 2; ++ks) {
      const int kb = ks * 16 + (lane >> 5) * 8;
      bf16x8 ah = ldfrag(&Ah[(wv * 32 + (lane & 31)) * 36 + kb]);
      bf16x8 al = ldfrag(&Al[(wv * 32 + (lane & 31)) * 36 + kb]);
      #pragma unroll
      for (int nt = 0; nt < 4; ++nt) {
        bf16x8 bh_ = ldfrag(&Bh[(nt * 32 + (lane & 31)) * 36 + kb]);
        bf16x8 bl_ = ldfrag(&Bl[(nt * 32 + (lane & 31)) * 36 + kb]);
        acc[nt] = __builtin_amdgcn_mfma_f32_32x32x16_bf16(ah, bh_, acc[nt], 0, 0, 0);
        acc[nt] = __builtin_amdgcn_mfma_f32_32x32x16_bf16(ah, bl_, acc[nt], 0, 0, 0);
        acc[nt] = __builtin_amdgcn_mfma_f32_32x32x16_bf16(al, bh_, acc[nt], 0, 0, 0);
      }
    }
  }

  // ---- S2: spectral I2 via MFMA into the same accumulators ----
  #pragma unroll
  for (int ks = 0; ks < 2; ++ks) {
    const int kb = ks * 16 + (lane >> 5) * 8;
    bf16x8 ya = ldfrag(&Ylds[(wv * 32 + (lane & 31)) * 36 + kb]);
    #pragma unroll
    for (int nt = 0; nt < 4; ++nt) {
      bf16x8 tb = ldfrag(&Tlds[(nt * 32 + (lane & 31)) * 36 + kb]);
      acc[nt] = __builtin_amdgcn_mfma_f32_32x32x16_bf16(ya, tb, acc[nt], 0, 0, 0);
    }
  }

  // ---- epilogue: activation + store (C/D layout: col=lane&31, row=(r&3)+8(r>>2)+4(lane>>5)) ----
  #pragma unroll
  for (int nt = 0; nt < 4; ++nt) {
    int w = nt * 32 + (lane & 31);
    #pragma unroll
    for (int r = 0; r < 16; ++r) {
      int o = wv * 32 + (r & 3) + 8 * (r >> 2) + 4 * (lane >> 5);
      float v = acc[nt][r];
      out[((size_t)(b * 128 + o)) * 16384 + (size_t)h * 128 + w] = v * __expf(-v * v);
    }
  }
}

extern "C" void kernel_launch(void* const* d_in, const int* in_sizes, int n_in,
                              void* d_out, int out_size, void* d_ws, size_t ws_size,
                              hipStream_t stream) {
  const float* x  = (const float*)d_in[0];
  const float* wr = (const float*)d_in[1];
  const float* wi = (const float*)d_in[2];
  const float* ur = (const float*)d_in[3];
  const float* ui = (const float*)d_in[4];
  const float* vr = (const float*)d_in[5];
  const float* vi = (const float*)d_in[6];
  const float* sw = (const float*)d_in[7];
  float* out  = (float*)d_out;
  float* ws   = (float*)d_ws;
  float* tab  = ws + TAB_OFF;
  float* xtop = ws + XTOP_OFF;
  float* z    = ws + Z_OFF;
  float* otop = ws + OTOP_OFF;

  hipLaunchKernelGGL(k_tab, dim3(64), dim3(256), 0, stream, tab);
  hipLaunchKernelGGL(k_fwd, dim3(128, 16), dim3(128), 0, stream, x, tab, xtop);
  hipLaunchKernelGGL(k_z,   dim3(16), dim3(256), 0, stream, xtop, vr, vi, z);
  hipLaunchKernelGGL(k_mix, dim3(32, 8), dim3(256), 0, stream, xtop, wr, wi, ur, ui, z, otop);
  hipLaunchKernelGGL(k_out, dim3(128, 16), dim3(256), 0, stream, x, sw, otop, tab, out);
}

// Round 4
// 219.023 us; speedup vs baseline: 3.8016x; 1.3137x over previous
//
#include <hip/hip_runtime.h>
#include <math.h>

// B=16, C=128, H=128, W=128, MODES=16, RANK=8
// ws layout (float offsets):
//   tab  @ 0      : 8 tables of 2048 floats each (see below)
//   xtop @ 16384  : (b, i, mn, {re,im})  16*128*256*2 = 1,048,576 floats
//   z    @ 1064960: (b, r, {re,im})      16*8*2 = 256 floats
//   otop @ 1065216: (b, o, mn, {re,im})  1,048,576 floats
#define TAB_OFF 0
#define XTOP_OFF 16384
#define Z_OFF (16384 + 1048576)
#define OTOP_OFF (Z_OFF + 256)

// table float offsets (each table [2048]):
//     0  T1C  [w][n]   cos(2pi wn/128)/128
//  2048  T1NS [w][n]  -sin(2pi wn/128)/128
//  4096  T2C  [h][m]   cos(2pi hm/128)
//  6144  T2S  [h][m]   sin(2pi hm/128)
//  8192  T2CT [m][h]   cos(2pi hm/128)
// 10240  T2ST [m][h]   sin(2pi hm/128)
// 12288  I2C  [w][n]   c_n*cos(2pi wn/128)/128   (c_0=1, else 2)
// 14336  I2NS [w][n]  -c_n*sin(2pi wn/128)/128

using bf16x8 = __attribute__((ext_vector_type(8))) short;
using s16x4  = __attribute__((ext_vector_type(4))) short;
using f32x16 = __attribute__((ext_vector_type(16))) float;

__device__ inline unsigned short bf_rnd(float v) {
  return (unsigned short)((__float_as_uint(v) + 0x8000u) >> 16);
}
__device__ inline void bf_split(float v, unsigned short& hi, unsigned short& lo) {
  unsigned u = __float_as_uint(v);
  hi = (unsigned short)(u >> 16);
  float r = v - __uint_as_float(u & 0xFFFF0000u);
  lo = (unsigned short)(__float_as_uint(r) >> 16);
}
__device__ inline bf16x8 ldfrag(const unsigned short* p) {
  s16x4 a = *(const s16x4*)p;        // ds_read_b64 (8B aligned)
  s16x4 b = *(const s16x4*)(p + 4);
  bf16x8 r;
  r[0] = a[0]; r[1] = a[1]; r[2] = a[2]; r[3] = a[3];
  r[4] = b[0]; r[5] = b[1]; r[6] = b[2]; r[7] = b[3];
  return r;
}

__global__ __launch_bounds__(256) void k_tab(float* __restrict__ tab) {
  int idx = blockIdx.x * 256 + threadIdx.x;
  if (idx >= 16384) return;
  int which = idx >> 11, rem = idx & 2047;
  int a, j;
  if (which == 4 || which == 5) { a = rem & 127; j = rem >> 7; }  // [m][h]
  else { a = rem >> 4; j = rem & 15; }
  int p = (a * j) & 127;  // exact phase reduction
  float ang = (float)p * (float)(3.14159265358979323846 / 64.0);
  float cv = cosf(ang), sv = sinf(ang);
  float v;
  switch (which) {
    case 0: v = cv * (1.f / 128.f); break;
    case 1: v = -sv * (1.f / 128.f); break;
    case 2: v = cv; break;
    case 3: v = sv; break;
    case 4: v = cv; break;
    case 5: v = sv; break;
    case 6: v = ((rem & 15) == 0 ? 1.f : 2.f) * cv * (1.f / 128.f); break;
    default: v = ((rem & 15) == 0 ? 1.f : 2.f) * (-sv) * (1.f / 128.f); break;
  }
  tab[idx] = v;
}

// Forward truncated DFT. Block = one (b,c) image, 128 threads (2 waves).
__global__ __launch_bounds__(128) void k_fwd(const float* __restrict__ x,
                                             const float* __restrict__ tab,
                                             float* __restrict__ xtop) {
  __shared__ float Ar[16][132];
  __shared__ float Ai[16][132];
  const int c = blockIdx.x, b = blockIdx.y;
  const int t = threadIdx.x;  // h = t
  const float* row = x + (((size_t)(b * 128 + c)) << 14) + (size_t)t * 128;

  float ar[16], ai[16];
  #pragma unroll
  for (int n = 0; n < 16; ++n) { ar[n] = 0.f; ai[n] = 0.f; }

  for (int w0 = 0; w0 < 128; w0 += 16) {
    float xv[16];
    #pragma unroll
    for (int q = 0; q < 4; ++q)
      *(float4*)&xv[q * 4] = *(const float4*)(row + w0 + q * 4);
    #pragma unroll
    for (int w = 0; w < 16; ++w) {
      const float* tc = tab + (w0 + w) * 16;          // uniform -> s_load
      const float* ts = tab + 2048 + (w0 + w) * 16;
      #pragma unroll
      for (int n = 0; n < 16; ++n) {
        ar[n] += xv[w] * tc[n];
        ai[n] += xv[w] * ts[n];
      }
    }
  }
  #pragma unroll
  for (int n = 0; n < 16; ++n) { Ar[n][t] = ar[n]; Ai[n][t] = ai[n]; }
  __syncthreads();

  const int n = t & 15, m0 = t >> 4;
  const float* tc0 = tab + 8192 + m0 * 128;
  const float* ts0 = tab + 10240 + m0 * 128;
  const float* tc1 = tc0 + 1024;
  const float* ts1 = ts0 + 1024;
  float xr0 = 0.f, xi0 = 0.f, xr1 = 0.f, xi1 = 0.f;
  for (int h4 = 0; h4 < 128; h4 += 4) {
    float arv[4], aiv[4], cc0[4], ss0[4], cc1[4], ss1[4];
    *(float4*)arv = *(const float4*)&Ar[n][h4];
    *(float4*)aiv = *(const float4*)&Ai[n][h4];
    *(float4*)cc0 = *(const float4*)(tc0 + h4);
    *(float4*)ss0 = *(const float4*)(ts0 + h4);
    *(float4*)cc1 = *(const float4*)(tc1 + h4);
    *(float4*)ss1 = *(const float4*)(ts1 + h4);
    #pragma unroll
    for (int j = 0; j < 4; ++j) {
      xr0 += arv[j] * cc0[j] + aiv[j] * ss0[j];
      xi0 += aiv[j] * cc0[j] - arv[j] * ss0[j];
      xr1 += arv[j] * cc1[j] + aiv[j] * ss1[j];
      xi1 += aiv[j] * cc1[j] - arv[j] * ss1[j];
    }
  }
  size_t base = ((size_t)(b * 128 + c)) * 512 + (size_t)t * 2;
  xtop[base] = xr0; xtop[base + 1] = xi0;
  xtop[base + 256] = xr1; xtop[base + 257] = xi1;
}

// z[b,r] += partial over i-chunk of sum_{i,mn} x_top[b,i,mn]*conj(V)[i,r,mn]
// Grid (16 b, 8 ichunks); z zeroed by memset beforehand.
__global__ __launch_bounds__(256) void k_z(const float* __restrict__ xtop,
                                           const float* __restrict__ vre,
                                           const float* __restrict__ vim,
                                           float* __restrict__ zout) {
  int b = blockIdx.x, ic = blockIdx.y, t = threadIdx.x;
  float zr[8], zi[8];
  #pragma unroll
  for (int r = 0; r < 8; ++r) { zr[r] = 0.f; zi[r] = 0.f; }
  const float* xb = xtop + ((size_t)b * 128) * 512;
  for (int i = ic * 16; i < ic * 16 + 16; ++i) {
    float xr = xb[i * 512 + t * 2], xi = xb[i * 512 + t * 2 + 1];
    #pragma unroll
    for (int r = 0; r < 8; ++r) {
      float vr = vre[(size_t)(i * 8 + r) * 256 + t];
      float vi = vim[(size_t)(i * 8 + r) * 256 + t];
      zr[r] += xr * vr + xi * vi;
      zi[r] += xi * vr - xr * vi;
    }
  }
  #pragma unroll
  for (int r = 0; r < 8; ++r)
    for (int off = 32; off > 0; off >>= 1) {
      zr[r] += __shfl_down(zr[r], off);
      zi[r] += __shfl_down(zi[r], off);
    }
  __shared__ float red[4][16];
  int wid = t >> 6, lane = t & 63;
  if (lane == 0) {
    #pragma unroll
    for (int r = 0; r < 8; ++r) { red[wid][r * 2] = zr[r]; red[wid][r * 2 + 1] = zi[r]; }
  }
  __syncthreads();
  if (t < 16) atomicAdd(&zout[b * 16 + t], red[0][t] + red[1][t] + red[2][t] + red[3][t]);
}

// otop[b,o,mn] += partial over i-chunk of sum_i D[o,i,mn]*x_top[b,i,mn]
// (+ sum_r U[o,r,mn]*z[b,r], added by the ic==0 chunk only).
// Grid (32 o-tiles, 8 b-pairs, 8 ichunks); otop zeroed by memset beforehand.
__global__ __launch_bounds__(256) void k_mix(const float* __restrict__ xtop,
                                             const float* __restrict__ wre,
                                             const float* __restrict__ wim,
                                             const float* __restrict__ ure,
                                             const float* __restrict__ uim,
                                             const float* __restrict__ z,
                                             float* __restrict__ otop) {
  int o0 = blockIdx.x * 4, b0 = blockIdx.y * 2, ic = blockIdx.z, t = threadIdx.x;
  float ar[2][4], ai[2][4];
  #pragma unroll
  for (int bb = 0; bb < 2; ++bb)
    #pragma unroll
    for (int oo = 0; oo < 4; ++oo) { ar[bb][oo] = 0.f; ai[bb][oo] = 0.f; }
  const float* x0 = xtop + ((size_t)(b0 * 128)) * 512;
  const float* x1 = x0 + 128 * 512;
  for (int i = ic * 16; i < ic * 16 + 16; ++i) {
    float x0r = x0[i * 512 + t * 2], x0i = x0[i * 512 + t * 2 + 1];
    float x1r = x1[i * 512 + t * 2], x1i = x1[i * 512 + t * 2 + 1];
    #pragma unroll
    for (int oo = 0; oo < 4; ++oo) {
      size_t di = (size_t)((o0 + oo) * 128 + i) * 256 + t;
      float dr = wre[di], dj = wim[di];
      ar[0][oo] += dr * x0r - dj * x0i; ai[0][oo] += dr * x0i + dj * x0r;
      ar[1][oo] += dr * x1r - dj * x1i; ai[1][oo] += dr * x1i + dj * x1r;
    }
  }
  if (ic == 0) {
    float zr[2][8], zi[2][8];
    #pragma unroll
    for (int bb = 0; bb < 2; ++bb)
      #pragma unroll
      for (int r = 0; r < 8; ++r) {
        zr[bb][r] = z[(b0 + bb) * 16 + r * 2];
        zi[bb][r] = z[(b0 + bb) * 16 + r * 2 + 1];
      }
    #pragma unroll
    for (int oo = 0; oo < 4; ++oo)
      #pragma unroll
      for (int r = 0; r < 8; ++r) {
        float urv = ure[(size_t)((o0 + oo) * 8 + r) * 256 + t];
        float uiv = uim[(size_t)((o0 + oo) * 8 + r) * 256 + t];
        #pragma unroll
        for (int bb = 0; bb < 2; ++bb) {
          ar[bb][oo] += urv * zr[bb][r] - uiv * zi[bb][r];
          ai[bb][oo] += urv * zi[bb][r] + uiv * zr[bb][r];
        }
      }
  }
  #pragma unroll
  for (int bb = 0; bb < 2; ++bb)
    #pragma unroll
    for (int oo = 0; oo < 4; ++oo) {
      size_t oi = ((size_t)((b0 + bb) * 128 + o0 + oo) * 256 + (size_t)t) * 2;
      atomicAdd(&otop[oi], ar[bb][oo]);
      atomicAdd(&otop[oi + 1], ai[bb][oo]);
    }
}

// Fused inverse-DFT + skip-GEMM + activation.
// Block = (h, b): output tile [128 o][128 w].
// Skip GEMM via 3-product split-bf16 MFMA (error ~2^-18); spectral I2 via
// plain-bf16 MFMA into the SAME accumulators; I1 (tiny) in fp32 VALU.
__global__ __launch_bounds__(256) void k_out(const float* __restrict__ x,
                                             const float* __restrict__ sw,
                                             const float* __restrict__ otop,
                                             const float* __restrict__ tab,
                                             float* __restrict__ out) {
  __shared__ unsigned short Ylds[128 * 36];  // [o][k]: k<16 Yr[n], k>=16 Yi[n]
  __shared__ unsigned short Tlds[128 * 36];  // [w][k]: k<16 I2C[w][n], k>=16 I2NS[w][n]
  __shared__ unsigned short Bh[128 * 36], Bl[128 * 36];  // x tile  [w][c_local]
  __shared__ unsigned short Ah[128 * 36], Al[128 * 36];  // sw tile [o][c_local]
  const int h = blockIdx.x, b = blockIdx.y;
  const int t = threadIdx.x;
  const int lane = t & 63, wv = t >> 6;

  // ---- build T' (bf16 I2 tables, concatenated cos|sin per w) ----
  {
    int w = t >> 1, half = t & 1;
    const float* src = tab + (half ? 14336 : 12288) + w * 16;
    #pragma unroll
    for (int q = 0; q < 4; ++q) {
      float4 v = *(const float4*)(src + q * 4);
      int k0 = half * 16 + q * 4;
      Tlds[w * 36 + k0 + 0] = bf_rnd(v.x);
      Tlds[w * 36 + k0 + 1] = bf_rnd(v.y);
      Tlds[w * 36 + k0 + 2] = bf_rnd(v.z);
      Tlds[w * 36 + k0 + 3] = bf_rnd(v.w);
    }
  }
  // ---- I1: Y[o][n] = sum_m X[o][m][n] e^{+2pi i m h/128} (fp32) ----
  {
    int o = t >> 1, nh = (t & 1) * 8;
    float yr[8], yi[8];
    #pragma unroll
    for (int j = 0; j < 8; ++j) { yr[j] = 0.f; yi[j] = 0.f; }
    const float* xb = otop + ((size_t)(b * 128 + o)) * 512 + nh * 2;
    #pragma unroll 4
    for (int m = 0; m < 16; ++m) {
      float cm = tab[4096 + h * 16 + m];   // uniform -> s_load
      float sm = tab[6144 + h * 16 + m];
      float4 q0 = *(const float4*)(xb + m * 32 + 0);
      float4 q1 = *(const float4*)(xb + m * 32 + 4);
      float4 q2 = *(const float4*)(xb + m * 32 + 8);
      float4 q3 = *(const float4*)(xb + m * 32 + 12);
      yr[0] += q0.x * cm - q0.y * sm; yi[0] += q0.x * sm + q0.y * cm;
      yr[1] += q0.z * cm - q0.w * sm; yi[1] += q0.z * sm + q0.w * cm;
      yr[2] += q1.x * cm - q1.y * sm; yi[2] += q1.x * sm + q1.y * cm;
      yr[3] += q1.z * cm - q1.w * sm; yi[3] += q1.z * sm + q1.w * cm;
      yr[4] += q2.x * cm - q2.y * sm; yi[4] += q2.x * sm + q2.y * cm;
      yr[5] += q2.z * cm - q2.w * sm; yi[5] += q2.z * sm + q2.w * cm;
      yr[6] += q3.x * cm - q3.y * sm; yi[6] += q3.x * sm + q3.y * cm;
      yr[7] += q3.z * cm - q3.w * sm; yi[7] += q3.z * sm + q3.w * cm;
    }
    #pragma unroll
    for (int j = 0; j < 8; ++j) {
      Ylds[o * 36 + nh + j] = bf_rnd(yr[j]);
      Ylds[o * 36 + 16 + nh + j] = bf_rnd(yi[j]);
    }
  }
  __syncthreads();

  f32x16 acc[4];
  #pragma unroll
  for (int nt = 0; nt < 4; ++nt)
    #pragma unroll
    for (int e = 0; e < 16; ++e) acc[nt][e] = 0.f;

  // ---- skip GEMM: C[o][w] = sum_c sw[o][c] x[b][c][h][w], K in 4 chunks ----
  for (int kc = 0; kc < 4; ++kc) {
    float xv[16], wv16[16];
    #pragma unroll
    for (int it = 0; it < 16; ++it) {
      int c = kc * 32 + it * 2 + (t >> 7);
      int w = t & 127;
      xv[it] = x[(size_t)(b * 128 + c) * 16384 + (size_t)h * 128 + w];
    }
    #pragma unroll
    for (int it = 0; it < 16; ++it) {
      int idx = it * 256 + t;
      int o = idx >> 5, cl = idx & 31;
      wv16[it] = sw[o * 128 + kc * 32 + cl];
    }
    __syncthreads();  // previous chunk's frag reads complete
    #pragma unroll
    for (int it = 0; it < 16; ++it) {
      int cl = it * 2 + (t >> 7);
      int w = t & 127;
      unsigned short hb, lb;
      bf_split(xv[it], hb, lb);
      Bh[w * 36 + cl] = hb; Bl[w * 36 + cl] = lb;
    }
    #pragma unroll
    for (int it = 0; it < 16; ++it) {
      int idx = it * 256 + t;
      int o = idx >> 5, cl = idx & 31;
      unsigned short hb, lb;
      bf_split(wv16[it], hb, lb);
      Ah[o * 36 + cl] = hb; Al[o * 36 + cl] = lb;
    }
    __syncthreads();
    #pragma unroll
    for (int ks = 0; ks < 2; ++ks) {
      const int kb = ks * 16 + (lane >> 5) * 8;
      bf16x8 ah = ldfrag(&Ah[(wv * 32 + (lane & 31)) * 36 + kb]);
      bf16x8 al = ldfrag(&Al[(wv * 32 + (lane & 31)) * 36 + kb]);
      #pragma unroll
      for (int nt = 0; nt < 4; ++nt) {
        bf16x8 bh_ = ldfrag(&Bh[(nt * 32 + (lane & 31)) * 36 + kb]);
        bf16x8 bl_ = ldfrag(&Bl[(nt * 32 + (lane & 31)) * 36 + kb]);
        acc[nt] = __builtin_amdgcn_mfma_f32_32x32x16_bf16(ah, bh_, acc[nt], 0, 0, 0);
        acc[nt] = __builtin_amdgcn_mfma_f32_32x32x16_bf16(ah, bl_, acc[nt], 0, 0, 0);
        acc[nt] = __builtin_amdgcn_mfma_f32_32x32x16_bf16(al, bh_, acc[nt], 0, 0, 0);
      }
    }
  }

  // ---- S2: spectral I2 via MFMA into the same accumulators ----
  #pragma unroll
  for (int ks = 0; ks < 2; ++ks) {
    const int kb = ks * 16 + (lane >> 5) * 8;
    bf16x8 ya = ldfrag(&Ylds[(wv * 32 + (lane & 31)) * 36 + kb]);
    #pragma unroll
    for (int nt = 0; nt < 4; ++nt) {
      bf16x8 tb = ldfrag(&Tlds[(nt * 32 + (lane & 31)) * 36 + kb]);
      acc[nt] = __builtin_amdgcn_mfma_f32_32x32x16_bf16(ya, tb, acc[nt], 0, 0, 0);
    }
  }

  // ---- epilogue: activation + store ----
  #pragma unroll
  for (int nt = 0; nt < 4; ++nt) {
    int w = nt * 32 + (lane & 31);
    #pragma unroll
    for (int r = 0; r < 16; ++r) {
      int o = wv * 32 + (r & 3) + 8 * (r >> 2) + 4 * (lane >> 5);
      float v = acc[nt][r];
      out[((size_t)(b * 128 + o)) * 16384 + (size_t)h * 128 + w] = v * __expf(-v * v);
    }
  }
}

extern "C" void kernel_launch(void* const* d_in, const int* in_sizes, int n_in,
                              void* d_out, int out_size, void* d_ws, size_t ws_size,
                              hipStream_t stream) {
  const float* x  = (const float*)d_in[0];
  const float* wr = (const float*)d_in[1];
  const float* wi = (const float*)d_in[2];
  const float* ur = (const float*)d_in[3];
  const float* ui = (const float*)d_in[4];
  const float* vr = (const float*)d_in[5];
  const float* vi = (const float*)d_in[6];
  const float* sw = (const float*)d_in[7];
  float* out  = (float*)d_out;
  float* ws   = (float*)d_ws;
  float* tab  = ws + TAB_OFF;
  float* xtop = ws + XTOP_OFF;
  float* z    = ws + Z_OFF;
  float* otop = ws + OTOP_OFF;

  hipMemsetAsync(z, 0, 256 * sizeof(float), stream);
  hipMemsetAsync(otop, 0, 1048576 * sizeof(float), stream);
  hipLaunchKernelGGL(k_tab, dim3(64), dim3(256), 0, stream, tab);
  hipLaunchKernelGGL(k_fwd, dim3(128, 16), dim3(128), 0, stream, x, tab, xtop);
  hipLaunchKernelGGL(k_z,   dim3(16, 8), dim3(256), 0, stream, xtop, vr, vi, z);
  hipLaunchKernelGGL(k_mix, dim3(32, 8, 8), dim3(256), 0, stream, xtop, wr, wi, ur, ui, z, otop);
  hipLaunchKernelGGL(k_out, dim3(128, 16), dim3(256), 0, stream, x, sw, otop, tab, out);
}

// Round 6
// 207.301 us; speedup vs baseline: 4.0166x; 1.0565x over previous
//
#include <hip/hip_runtime.h>
#include <math.h>

// B=16, C=128, H=128, W=128, MODES=16, RANK=8
// ws layout (float offsets):
//   tab  @ 0      : 8 tables of 2048 floats each (see below)
//   xtop @ 16384  : (b, i, mn, {re,im})  16*128*256*2 = 1,048,576 floats
//   z    @ 1064960: (b, r, {re,im})      16*8*2 = 256 floats
//   otop @ 1065216: (b, o, mn, {re,im})  1,048,576 floats
//   tf   @ 2113792: split-bf16 F1 DFT table, plain layout [part][n'][k], 8192 shorts
#define TAB_OFF 0
#define XTOP_OFF 16384
#define Z_OFF (16384 + 1048576)
#define OTOP_OFF (Z_OFF + 256)
#define TF_OFF (OTOP_OFF + 1048576)

// table float offsets (each table [2048]):
//     0  T1C  [w][n]   cos(2pi wn/128)/128
//  2048  T1NS [w][n]  -sin(2pi wn/128)/128
//  4096  T2C  [h][m]   cos(2pi hm/128)
//  6144  T2S  [h][m]   sin(2pi hm/128)
//  8192  T2CT [m][h]   cos(2pi hm/128)
// 10240  T2ST [m][h]   sin(2pi hm/128)
// 12288  I2C  [w][n]   c_n*cos(2pi wn/128)/128   (c_0=1, else 2)
// 14336  I2NS [w][n]  -c_n*sin(2pi wn/128)/128

using bf16x8 = __attribute__((ext_vector_type(8))) short;
using s16x4  = __attribute__((ext_vector_type(4))) short;
using f32x16 = __attribute__((ext_vector_type(16))) float;

__device__ inline unsigned short bf_rnd(float v) {
  return (unsigned short)((__float_as_uint(v) + 0x8000u) >> 16);
}
__device__ inline void bf_split(float v, unsigned short& hi, unsigned short& lo) {
  unsigned u = __float_as_uint(v);
  hi = (unsigned short)(u >> 16);
  float r = v - __uint_as_float(u & 0xFFFF0000u);
  lo = (unsigned short)(__float_as_uint(r) >> 16);
}
__device__ inline bf16x8 ldfrag(const unsigned short* p) {
  s16x4 a = *(const s16x4*)p;        // ds_read_b64 (8B aligned)
  s16x4 b = *(const s16x4*)(p + 4);
  bf16x8 r;
  r[0] = a[0]; r[1] = a[1]; r[2] = a[2]; r[3] = a[3];
  r[4] = b[0]; r[5] = b[1]; r[6] = b[2]; r[7] = b[3];
  return r;
}
// swizzled frag read from a [rows][128-short] LDS tile, row stride 256 B:
// byte ^= (row&7)<<4 (same XOR applied on the write side).
__device__ inline bf16x8 ldfrag_sw(const unsigned short* base, int row, int koff) {
  int byte = row * 256 + ((koff * 2) ^ ((row & 7) << 4));
  return ldfrag((const unsigned short*)((const char*)base + byte));
}

__global__ __launch_bounds__(256) void k_tab(float* __restrict__ tab) {
  int idx = blockIdx.x * 256 + threadIdx.x;
  if (idx >= 16384) return;
  int which = idx >> 11, rem = idx & 2047;
  int a, j;
  if (which == 4 || which == 5) { a = rem & 127; j = rem >> 7; }  // [m][h]
  else { a = rem >> 4; j = rem & 15; }
  int p = (a * j) & 127;  // exact phase reduction
  float ang = (float)p * (float)(3.14159265358979323846 / 64.0);
  float cv = cosf(ang), sv = sinf(ang);
  float v;
  switch (which) {
    case 0: v = cv * (1.f / 128.f); break;
    case 1: v = -sv * (1.f / 128.f); break;
    case 2: v = cv; break;
    case 3: v = sv; break;
    case 4: v = cv; break;
    case 5: v = sv; break;
    case 6: v = ((rem & 15) == 0 ? 1.f : 2.f) * cv * (1.f / 128.f); break;
    default: v = ((rem & 15) == 0 ? 1.f : 2.f) * (-sv) * (1.f / 128.f); break;
  }
  tab[idx] = v;
}

// F1 table, split hi/lo, plain layout tf[part*4096 + n'*128 + k]:
// n'<16: cos(2pi k n'/128)/128 ; n'>=16: -sin(2pi k (n'-16)/128)/128
__global__ __launch_bounds__(256) void k_fprep(unsigned short* __restrict__ tf) {
  int idx = blockIdx.x * 256 + threadIdx.x;  // [0,4096)
  if (idx >= 4096) return;
  int np = idx >> 7, k = idx & 127;
  int n = np & 15;
  int p = (k * n) & 127;
  float ang = (float)p * (float)(3.14159265358979323846 / 64.0);
  float v = (np < 16 ? cosf(ang) : -sinf(ang)) * (1.f / 128.f);
  unsigned short hi, lo;
  bf_split(v, hi, lo);
  tf[np * 128 + k] = hi;
  tf[4096 + np * 128 + k] = lo;
}

// Forward truncated DFT via MFMA. Block = one (b,c) image, 256 threads (4 waves).
// F1: A[h][n'] = sum_w xbf16[h][w] * (Tfh+Tfl)[w][n']  (MFMA, N=32 cos|sin concat)
// F2: X[m][n] = sum_h A[h][n] e^{-2pi i m h/128}        (fp32 VALU, via LDS transpose)
__global__ __launch_bounds__(256) void k_fwd(const float* __restrict__ x,
                                             const unsigned short* __restrict__ tf,
                                             const float* __restrict__ tab,
                                             float* __restrict__ xtop) {
  __shared__ unsigned short Xh[128 * 128];   // [h][w] bf16, swizzled; later aliased by Ar/Ai
  __shared__ unsigned short Tfh[32 * 128];   // [n'][k] swizzled
  __shared__ unsigned short Tfl[32 * 128];
  const int c = blockIdx.x, b = blockIdx.y;
  const int t = threadIdx.x;
  const int lane = t & 63, wv = t >> 6;

  // ---- stage Tf (8192 shorts) ----
  #pragma unroll
  for (int it = 0; it < 32; ++it) {
    int idx = it * 256 + t;                  // [0,8192)
    int part = idx >> 12, rem = idx & 4095;
    int row = rem >> 7, k = rem & 127;
    unsigned short v = tf[part * 4096 + rem];
    unsigned short* dst = part ? Tfl : Tfh;
    *(unsigned short*)((char*)dst + row * 256 + ((k * 2) ^ ((row & 7) << 4))) = v;
  }
  // ---- stage x as bf16 (coalesced float4 reads) ----
  const float* img = x + (((size_t)(b * 128 + c)) << 14);
  #pragma unroll
  for (int it = 0; it < 16; ++it) {
    int flat = it * 256 + t;                 // [0,4096)
    int h = flat >> 5, wq = flat & 31;
    float4 v = *(const float4*)(img + (size_t)flat * 4);
    s16x4 pk;
    pk[0] = (short)bf_rnd(v.x); pk[1] = (short)bf_rnd(v.y);
    pk[2] = (short)bf_rnd(v.z); pk[3] = (short)bf_rnd(v.w);
    *(s16x4*)((char*)Xh + h * 256 + ((wq * 8) ^ ((h & 7) << 4))) = pk;
  }
  __syncthreads();

  // ---- F1 MFMA: wave wv owns h-rows [wv*32, wv*32+32) ----
  f32x16 acc;
  #pragma unroll
  for (int e = 0; e < 16; ++e) acc[e] = 0.f;
  const int orow = wv * 32 + (lane & 31);
  const int bcol = lane & 31;
  const int kh8 = (lane >> 5) * 8;
  #pragma unroll
  for (int kc8 = 0; kc8 < 8; ++kc8) {        // 8 k-steps of 16
    int kfull = kc8 * 16 + kh8;
    bf16x8 a  = ldfrag_sw(Xh, orow, kfull);
    bf16x8 th = ldfrag_sw(Tfh, bcol, kfull);
    bf16x8 tl = ldfrag_sw(Tfl, bcol, kfull);
    acc = __builtin_amdgcn_mfma_f32_32x32x16_bf16(a, th, acc, 0, 0, 0);
    acc = __builtin_amdgcn_mfma_f32_32x32x16_bf16(a, tl, acc, 0, 0, 0);
  }
  __syncthreads();  // all frag reads of Xh done before aliasing it

  // ---- write A to transpose buffers Ar[n][h], Ai[n][h] (alias Xh region) ----
  float* Arp = (float*)Xh;          // [16][132]
  float* Aip = Arp + 16 * 132;      // [16][132]; total 16896 B <= 32768 B
  {
    const int col = lane & 31;
    #pragma unroll
    for (int r = 0; r < 16; ++r) {
      int h = wv * 32 + (r & 3) + 8 * (r >> 2) + 4 * (lane >> 5);
      if (col < 16) Arp[col * 132 + h] = acc[r];
      else          Aip[(col - 16) * 132 + h] = acc[r];
    }
  }
  __syncthreads();

  // ---- F2 (fp32): thread t -> (m = t>>4, n = t&15) ----
  {
    const int m = t >> 4, n = t & 15;
    const float* tc = tab + 8192 + m * 128;   // T2CT[m][h]
    const float* ts = tab + 10240 + m * 128;  // T2ST[m][h]
    const float* ar = Arp + n * 132;
    const float* ai = Aip + n * 132;
    float xr = 0.f, xi = 0.f;
    #pragma unroll 8
    for (int h4 = 0; h4 < 128; h4 += 4) {
      float4 av = *(const float4*)(ar + h4);
      float4 iv = *(const float4*)(ai + h4);
      float4 cv = *(const float4*)(tc + h4);
      float4 sv = *(const float4*)(ts + h4);
      xr += av.x * cv.x + iv.x * sv.x;  xi += iv.x * cv.x - av.x * sv.x;
      xr += av.y * cv.y + iv.y * sv.y;  xi += iv.y * cv.y - av.y * sv.y;
      xr += av.z * cv.z + iv.z * sv.z;  xi += iv.z * cv.z - av.z * sv.z;
      xr += av.w * cv.w + iv.w * sv.w;  xi += iv.w * cv.w - av.w * sv.w;
    }
    size_t base = ((size_t)(b * 128 + c)) * 512 + (size_t)(m * 16 + n) * 2;
    xtop[base] = xr; xtop[base + 1] = xi;
  }
}

// z[b,r] += partial over i-chunk; z zeroed by memset beforehand.
__global__ __launch_bounds__(256) void k_z(const float* __restrict__ xtop,
                                           const float* __restrict__ vre,
                                           const float* __restrict__ vim,
                                           float* __restrict__ zout) {
  int b = blockIdx.x, ic = blockIdx.y, t = threadIdx.x;
  float zr[8], zi[8];
  #pragma unroll
  for (int r = 0; r < 8; ++r) { zr[r] = 0.f; zi[r] = 0.f; }
  const float* xb = xtop + ((size_t)b * 128) * 512;
  for (int i = ic * 16; i < ic * 16 + 16; ++i) {
    float xr = xb[i * 512 + t * 2], xi = xb[i * 512 + t * 2 + 1];
    #pragma unroll
    for (int r = 0; r < 8; ++r) {
      float vr = vre[(size_t)(i * 8 + r) * 256 + t];
      float vi = vim[(size_t)(i * 8 + r) * 256 + t];
      zr[r] += xr * vr + xi * vi;
      zi[r] += xi * vr - xr * vi;
    }
  }
  #pragma unroll
  for (int r = 0; r < 8; ++r)
    for (int off = 32; off > 0; off >>= 1) {
      zr[r] += __shfl_down(zr[r], off);
      zi[r] += __shfl_down(zi[r], off);
    }
  __shared__ float red[4][16];
  int wid = t >> 6, lane = t & 63;
  if (lane == 0) {
    #pragma unroll
    for (int r = 0; r < 8; ++r) { red[wid][r * 2] = zr[r]; red[wid][r * 2 + 1] = zi[r]; }
  }
  __syncthreads();
  if (t < 16) atomicAdd(&zout[b * 16 + t], red[0][t] + red[1][t] + red[2][t] + red[3][t]);
}

// otop[b,o,mn] += partial over i-chunk (+ U z term from ic==0 chunk).
__global__ __launch_bounds__(256) void k_mix(const float* __restrict__ xtop,
                                             const float* __restrict__ wre,
                                             const float* __restrict__ wim,
                                             const float* __restrict__ ure,
                                             const float* __restrict__ uim,
                                             const float* __restrict__ z,
                                             float* __restrict__ otop) {
  int o0 = blockIdx.x * 4, b0 = blockIdx.y * 2, ic = blockIdx.z, t = threadIdx.x;
  float ar[2][4], ai[2][4];
  #pragma unroll
  for (int bb = 0; bb < 2; ++bb)
    #pragma unroll
    for (int oo = 0; oo < 4; ++oo) { ar[bb][oo] = 0.f; ai[bb][oo] = 0.f; }
  const float* x0 = xtop + ((size_t)(b0 * 128)) * 512;
  const float* x1 = x0 + 128 * 512;
  for (int i = ic * 16; i < ic * 16 + 16; ++i) {
    float x0r = x0[i * 512 + t * 2], x0i = x0[i * 512 + t * 2 + 1];
    float x1r = x1[i * 512 + t * 2], x1i = x1[i * 512 + t * 2 + 1];
    #pragma unroll
    for (int oo = 0; oo < 4; ++oo) {
      size_t di = (size_t)((o0 + oo) * 128 + i) * 256 + t;
      float dr = wre[di], dj = wim[di];
      ar[0][oo] += dr * x0r - dj * x0i; ai[0][oo] += dr * x0i + dj * x0r;
      ar[1][oo] += dr * x1r - dj * x1i; ai[1][oo] += dr * x1i + dj * x1r;
    }
  }
  if (ic == 0) {
    float zr[2][8], zi[2][8];
    #pragma unroll
    for (int bb = 0; bb < 2; ++bb)
      #pragma unroll
      for (int r = 0; r < 8; ++r) {
        zr[bb][r] = z[(b0 + bb) * 16 + r * 2];
        zi[bb][r] = z[(b0 + bb) * 16 + r * 2 + 1];
      }
    #pragma unroll
    for (int oo = 0; oo < 4; ++oo)
      #pragma unroll
      for (int r = 0; r < 8; ++r) {
        float urv = ure[(size_t)((o0 + oo) * 8 + r) * 256 + t];
        float uiv = uim[(size_t)((o0 + oo) * 8 + r) * 256 + t];
        #pragma unroll
        for (int bb = 0; bb < 2; ++bb) {
          ar[bb][oo] += urv * zr[bb][r] - uiv * zi[bb][r];
          ai[bb][oo] += urv * zi[bb][r] + uiv * zr[bb][r];
        }
      }
  }
  #pragma unroll
  for (int bb = 0; bb < 2; ++bb)
    #pragma unroll
    for (int oo = 0; oo < 4; ++oo) {
      size_t oi = ((size_t)((b0 + bb) * 128 + o0 + oo) * 256 + (size_t)t) * 2;
      atomicAdd(&otop[oi], ar[bb][oo]);
      atomicAdd(&otop[oi + 1], ai[bb][oo]);
    }
}

// Fused inverse-DFT + skip-GEMM + activation (round-4 verified version).
// Block = (h, b): output tile [128 o][128 w].
__global__ __launch_bounds__(256) void k_out(const float* __restrict__ x,
                                             const float* __restrict__ sw,
                                             const float* __restrict__ otop,
                                             const float* __restrict__ tab,
                                             float* __restrict__ out) {
  __shared__ unsigned short Ylds[128 * 36];  // [o][k]: k<16 Yr[n], k>=16 Yi[n]
  __shared__ unsigned short Tlds[128 * 36];  // [w][k]: k<16 I2C[w][n], k>=16 I2NS[w][n]
  __shared__ unsigned short Bh[128 * 36], Bl[128 * 36];  // x tile  [w][c_local]
  __shared__ unsigned short Ah[128 * 36], Al[128 * 36];  // sw tile [o][c_local]
  const int h = blockIdx.x, b = blockIdx.y;
  const int t = threadIdx.x;
  const int lane = t & 63, wv = t >> 6;

  // ---- build T' (bf16 I2 tables, concatenated cos|sin per w) ----
  {
    int w = t >> 1, half = t & 1;
    const float* src = tab + (half ? 14336 : 12288) + w * 16;
    #pragma unroll
    for (int q = 0; q < 4; ++q) {
      float4 v = *(const float4*)(src + q * 4);
      int k0 = half * 16 + q * 4;
      Tlds[w * 36 + k0 + 0] = bf_rnd(v.x);
      Tlds[w * 36 + k0 + 1] = bf_rnd(v.y);
      Tlds[w * 36 + k0 + 2] = bf_rnd(v.z);
      Tlds[w * 36 + k0 + 3] = bf_rnd(v.w);
    }
  }
  // ---- I1: Y[o][n] = sum_m X[o][m][n] e^{+2pi i m h/128} (fp32) ----
  {
    int o = t >> 1, nh = (t & 1) * 8;
    float yr[8], yi[8];
    #pragma unroll
    for (int j = 0; j < 8; ++j) { yr[j] = 0.f; yi[j] = 0.f; }
    const float* xb = otop + ((size_t)(b * 128 + o)) * 512 + nh * 2;
    #pragma unroll 4
    for (int m = 0; m < 16; ++m) {
      float cm = tab[4096 + h * 16 + m];   // uniform -> s_load
      float sm = tab[6144 + h * 16 + m];
      float4 q0 = *(const float4*)(xb + m * 32 + 0);
      float4 q1 = *(const float4*)(xb + m * 32 + 4);
      float4 q2 = *(const float4*)(xb + m * 32 + 8);
      float4 q3 = *(const float4*)(xb + m * 32 + 12);
      yr[0] += q0.x * cm - q0.y * sm; yi[0] += q0.x * sm + q0.y * cm;
      yr[1] += q0.z * cm - q0.w * sm; yi[1] += q0.z * sm + q0.w * cm;
      yr[2] += q1.x * cm - q1.y * sm; yi[2] += q1.x * sm + q1.y * cm;
      yr[3] += q1.z * cm - q1.w * sm; yi[3] += q1.z * sm + q1.w * cm;
      yr[4] += q2.x * cm - q2.y * sm; yi[4] += q2.x * sm + q2.y * cm;
      yr[5] += q2.z * cm - q2.w * sm; yi[5] += q2.z * sm + q2.w * cm;
      yr[6] += q3.x * cm - q3.y * sm; yi[6] += q3.x * sm + q3.y * cm;
      yr[7] += q3.z * cm - q3.w * sm; yi[7] += q3.z * sm + q3.w * cm;
    }
    #pragma unroll
    for (int j = 0; j < 8; ++j) {
      Ylds[o * 36 + nh + j] = bf_rnd(yr[j]);
      Ylds[o * 36 + 16 + nh + j] = bf_rnd(yi[j]);
    }
  }
  __syncthreads();

  f32x16 acc[4];
  #pragma unroll
  for (int nt = 0; nt < 4; ++nt)
    #pragma unroll
    for (int e = 0; e < 16; ++e) acc[nt][e] = 0.f;

  // ---- skip GEMM: C[o][w] = sum_c sw[o][c] x[b][c][h][w], K in 4 chunks ----
  for (int kc = 0; kc < 4; ++kc) {
    float xv[16], wv16[16];
    #pragma unroll
    for (int it = 0; it < 16; ++it) {
      int c = kc * 32 + it * 2 + (t >> 7);
      int w = t & 127;
      xv[it] = x[(size_t)(b * 128 + c) * 16384 + (size_t)h * 128 + w];
    }
    #pragma unroll
    for (int it = 0; it < 16; ++it) {
      int idx = it * 256 + t;
      int o = idx >> 5, cl = idx & 31;
      wv16[it] = sw[o * 128 + kc * 32 + cl];
    }
    __syncthreads();  // previous chunk's frag reads complete
    #pragma unroll
    for (int it = 0; it < 16; ++it) {
      int cl = it * 2 + (t >> 7);
      int w = t & 127;
      unsigned short hb, lb;
      bf_split(xv[it], hb, lb);
      Bh[w * 36 + cl] = hb; Bl[w * 36 + cl] = lb;
    }
    #pragma unroll
    for (int it = 0; it < 16; ++it) {
      int idx = it * 256 + t;
      int o = idx >> 5, cl = idx & 31;
      unsigned short hb, lb;
      bf_split(wv16[it], hb, lb);
      Ah[o * 36 + cl] = hb; Al[o * 36 + cl] = lb;
    }
    __syncthreads();
    #pragma unroll
    for (int ks = 0; ks < 2; ++ks) {
      const int kb = ks * 16 + (lane >> 5) * 8;
      bf16x8 ah = ldfrag(&Ah[(wv * 32 + (lane & 31)) * 36 + kb]);
      bf16x8 al = ldfrag(&Al[(wv * 32 + (lane & 31)) * 36 + kb]);
      #pragma unroll
      for (int nt = 0; nt < 4; ++nt) {
        bf16x8 bh_ = ldfrag(&Bh[(nt * 32 + (lane & 31)) * 36 + kb]);
        bf16x8 bl_ = ldfrag(&Bl[(nt * 32 + (lane & 31)) * 36 + kb]);
        acc[nt] = __builtin_amdgcn_mfma_f32_32x32x16_bf16(ah, bh_, acc[nt], 0, 0, 0);
        acc[nt] = __builtin_amdgcn_mfma_f32_32x32x16_bf16(ah, bl_, acc[nt], 0, 0, 0);
        acc[nt] = __builtin_amdgcn_mfma_f32_32x32x16_bf16(al, bh_, acc[nt], 0, 0, 0);
      }
    }
  }

  // ---- S2: spectral I2 via MFMA into the same accumulators ----
  #pragma unroll
  for (int ks = 0; ks < 2; ++ks) {
    const int kb = ks * 16 + (lane >> 5) * 8;
    bf16x8 ya = ldfrag(&Ylds[(wv * 32 + (lane & 31)) * 36 + kb]);
    #pragma unroll
    for (int nt = 0; nt < 4; ++nt) {
      bf16x8 tb = ldfrag(&Tlds[(nt * 32 + (lane & 31)) * 36 + kb]);
      acc[nt] = __builtin_amdgcn_mfma_f32_32x32x16_bf16(ya, tb, acc[nt], 0, 0, 0);
    }
  }

  // ---- epilogue: activation + store ----
  #pragma unroll
  for (int nt = 0; nt < 4; ++nt) {
    int w = nt * 32 + (lane & 31);
    #pragma unroll
    for (int r = 0; r < 16; ++r) {
      int o = wv * 32 + (r & 3) + 8 * (r >> 2) + 4 * (lane >> 5);
      float v = acc[nt][r];
      out[((size_t)(b * 128 + o)) * 16384 + (size_t)h * 128 + w] = v * __expf(-v * v);
    }
  }
}

extern "C" void kernel_launch(void* const* d_in, const int* in_sizes, int n_in,
                              void* d_out, int out_size, void* d_ws, size_t ws_size,
                              hipStream_t stream) {
  const float* x  = (const float*)d_in[0];
  const float* wr = (const float*)d_in[1];
  const float* wi = (const float*)d_in[2];
  const float* ur = (const float*)d_in[3];
  const float* ui = (const float*)d_in[4];
  const float* vr = (const float*)d_in[5];
  const float* vi = (const float*)d_in[6];
  const float* sw = (const float*)d_in[7];
  float* out  = (float*)d_out;
  float* ws   = (float*)d_ws;
  float* tab  = ws + TAB_OFF;
  float* xtop = ws + XTOP_OFF;
  float* z    = ws + Z_OFF;
  float* otop = ws + OTOP_OFF;
  unsigned short* tf = (unsigned short*)(ws + TF_OFF);

  hipMemsetAsync(z, 0, 256 * sizeof(float), stream);
  hipMemsetAsync(otop, 0, 1048576 * sizeof(float), stream);
  hipLaunchKernelGGL(k_tab, dim3(64), dim3(256), 0, stream, tab);
  hipLaunchKernelGGL(k_fprep, dim3(16), dim3(256), 0, stream, tf);
  hipLaunchKernelGGL(k_fwd, dim3(128, 16), dim3(256), 0, stream, x, tf, tab, xtop);
  hipLaunchKernelGGL(k_z,   dim3(16, 8), dim3(256), 0, stream, xtop, vr, vi, z);
  hipLaunchKernelGGL(k_mix, dim3(32, 8, 8), dim3(256), 0, stream, xtop, wr, wi, ur, ui, z, otop);
  hipLaunchKernelGGL(k_out, dim3(128, 16), dim3(256), 0, stream, x, sw, otop, tab, out);
}

// Round 7
// 202.182 us; speedup vs baseline: 4.1183x; 1.0253x over previous
//
#include <hip/hip_runtime.h>
#include <math.h>

// B=16, C=128, H=128, W=128, MODES=16, RANK=8
// ws layout (float offsets):
//   tab  @ 0      : 8 tables of 2048 floats each (see below)
//   xtop @ 16384  : (b, i, mn, {re,im})  16*128*256*2 = 1,048,576 floats
//                   NOTE: after k_mix, the first 16384 floats of this region are
//                   reused as swf (split-bf16 skip_w in MFMA A-frag order, 32768 shorts)
//   z    @ 1064960: (b, r, {re,im})      16*8*2 = 256 floats
//   otop @ 1065216: (b, o, mn, {re,im})  1,048,576 floats
//   tf   @ 2113792: split-bf16 F1 DFT table, plain layout [part][n'][k], 8192 shorts
#define TAB_OFF 0
#define XTOP_OFF 16384
#define Z_OFF (16384 + 1048576)
#define OTOP_OFF (Z_OFF + 256)
#define TF_OFF (OTOP_OFF + 1048576)
#define SWF_OFF XTOP_OFF   // aliases xtop, written by k_wprep AFTER k_mix

// table float offsets (each table [2048]):
//     0  T1C  [w][n]   cos(2pi wn/128)/128      (dead since round 6)
//  2048  T1NS [w][n]  -sin(2pi wn/128)/128      (dead since round 6)
//  4096  T2C  [h][m]   cos(2pi hm/128)
//  6144  T2S  [h][m]   sin(2pi hm/128)
//  8192  T2CT [m][h]   cos(2pi hm/128)
// 10240  T2ST [m][h]   sin(2pi hm/128)
// 12288  I2C  [w][n]   c_n*cos(2pi wn/128)/128   (c_0=1, else 2)
// 14336  I2NS [w][n]  -c_n*sin(2pi wn/128)/128

using bf16x8 = __attribute__((ext_vector_type(8))) short;
using s16x4  = __attribute__((ext_vector_type(4))) short;
using f32x16 = __attribute__((ext_vector_type(16))) float;

__device__ inline unsigned short bf_rnd(float v) {
  return (unsigned short)((__float_as_uint(v) + 0x8000u) >> 16);
}
__device__ inline void bf_split(float v, unsigned short& hi, unsigned short& lo) {
  unsigned u = __float_as_uint(v);
  hi = (unsigned short)(u >> 16);
  float r = v - __uint_as_float(u & 0xFFFF0000u);
  lo = (unsigned short)(__float_as_uint(r) >> 16);
}
__device__ inline bf16x8 ldfrag(const unsigned short* p) {
  s16x4 a = *(const s16x4*)p;        // ds_read_b64 (8B aligned)
  s16x4 b = *(const s16x4*)(p + 4);
  bf16x8 r;
  r[0] = a[0]; r[1] = a[1]; r[2] = a[2]; r[3] = a[3];
  r[4] = b[0]; r[5] = b[1]; r[6] = b[2]; r[7] = b[3];
  return r;
}
// swizzled frag read from a [rows][128-short] LDS tile, row stride 256 B:
// byte ^= (row&7)<<4 (same XOR applied on the write side).
__device__ inline bf16x8 ldfrag_sw(const unsigned short* base, int row, int koff) {
  int byte = row * 256 + ((koff * 2) ^ ((row & 7) << 4));
  return ldfrag((const unsigned short*)((const char*)base + byte));
}

__global__ __launch_bounds__(256) void k_tab(float* __restrict__ tab) {
  int idx = blockIdx.x * 256 + threadIdx.x;
  if (idx >= 16384) return;
  int which = idx >> 11, rem = idx & 2047;
  int a, j;
  if (which == 4 || which == 5) { a = rem & 127; j = rem >> 7; }  // [m][h]
  else { a = rem >> 4; j = rem & 15; }
  int p = (a * j) & 127;  // exact phase reduction
  float ang = (float)p * (float)(3.14159265358979323846 / 64.0);
  float cv = cosf(ang), sv = sinf(ang);
  float v;
  switch (which) {
    case 0: v = cv * (1.f / 128.f); break;
    case 1: v = -sv * (1.f / 128.f); break;
    case 2: v = cv; break;
    case 3: v = sv; break;
    case 4: v = cv; break;
    case 5: v = sv; break;
    case 6: v = ((rem & 15) == 0 ? 1.f : 2.f) * cv * (1.f / 128.f); break;
    default: v = ((rem & 15) == 0 ? 1.f : 2.f) * (-sv) * (1.f / 128.f); break;
  }
  tab[idx] = v;
}

// F1 table, split hi/lo, plain layout tf[part*4096 + n'*128 + k]:
// n'<16: cos(2pi k n'/128)/128 ; n'>=16: -sin(2pi k (n'-16)/128)/128
__global__ __launch_bounds__(256) void k_fprep(unsigned short* __restrict__ tf) {
  int idx = blockIdx.x * 256 + threadIdx.x;  // [0,4096)
  if (idx >= 4096) return;
  int np = idx >> 7, k = idx & 127;
  int n = np & 15;
  int p = (k * n) & 127;
  float ang = (float)p * (float)(3.14159265358979323846 / 64.0);
  float v = (np < 16 ? cosf(ang) : -sinf(ang)) * (1.f / 128.f);
  unsigned short hi, lo;
  bf_split(v, hi, lo);
  tf[np * 128 + k] = hi;
  tf[4096 + np * 128 + k] = lo;
}

// Split skip_w into hi/lo bf16 and store in MFMA A-frag order:
// element k of row o (k = kc*32 + ks*16 + kh*8 + j) lands at
// swf[((kc*2+ks)*2+part)*2048 + o*16 + kh*8 + j].
// A wave (o = w*32..w*32+31, kh = lane>>5) then reads one contiguous 1 KB line
// per (kc,ks,part) table with four 16 B loads.
__global__ __launch_bounds__(256) void k_wprep(const float* __restrict__ sw,
                                               unsigned short* __restrict__ swf) {
  int idx = blockIdx.x * 256 + threadIdx.x;
  if (idx >= 16384) return;
  int o = idx >> 7, k = idx & 127;
  unsigned short hb, lb;
  bf_split(sw[o * 128 + k], hb, lb);
  int kc = k >> 5, ks = (k >> 4) & 1, kh = (k >> 3) & 1, j = k & 7;
  int f0 = (kc * 2 + ks) * 2;
  swf[(f0 + 0) * 2048 + o * 16 + kh * 8 + j] = hb;
  swf[(f0 + 1) * 2048 + o * 16 + kh * 8 + j] = lb;
}

// Forward truncated DFT via MFMA. Block = one (b,c) image, 256 threads (4 waves).
// F1: A[h][n'] = sum_w xbf16[h][w] * (Tfh+Tfl)[w][n']  (MFMA, N=32 cos|sin concat)
// F2: X[m][n] = sum_h A[h][n] e^{-2pi i m h/128}        (fp32 VALU, via LDS transpose)
__global__ __launch_bounds__(256) void k_fwd(const float* __restrict__ x,
                                             const unsigned short* __restrict__ tf,
                                             const float* __restrict__ tab,
                                             float* __restrict__ xtop) {
  __shared__ unsigned short Xh[128 * 128];   // [h][w] bf16, swizzled; later aliased by Ar/Ai
  __shared__ unsigned short Tfh[32 * 128];   // [n'][k] swizzled
  __shared__ unsigned short Tfl[32 * 128];
  const int c = blockIdx.x, b = blockIdx.y;
  const int t = threadIdx.x;
  const int lane = t & 63, wv = t >> 6;

  // ---- stage Tf (8192 shorts) ----
  #pragma unroll
  for (int it = 0; it < 32; ++it) {
    int idx = it * 256 + t;                  // [0,8192)
    int part = idx >> 12, rem = idx & 4095;
    int row = rem >> 7, k = rem & 127;
    unsigned short v = tf[part * 4096 + rem];
    unsigned short* dst = part ? Tfl : Tfh;
    *(unsigned short*)((char*)dst + row * 256 + ((k * 2) ^ ((row & 7) << 4))) = v;
  }
  // ---- stage x as bf16 (coalesced float4 reads) ----
  const float* img = x + (((size_t)(b * 128 + c)) << 14);
  #pragma unroll
  for (int it = 0; it < 16; ++it) {
    int flat = it * 256 + t;                 // [0,4096)
    int h = flat >> 5, wq = flat & 31;
    float4 v = *(const float4*)(img + (size_t)flat * 4);
    s16x4 pk;
    pk[0] = (short)bf_rnd(v.x); pk[1] = (short)bf_rnd(v.y);
    pk[2] = (short)bf_rnd(v.z); pk[3] = (short)bf_rnd(v.w);
    *(s16x4*)((char*)Xh + h * 256 + ((wq * 8) ^ ((h & 7) << 4))) = pk;
  }
  __syncthreads();

  // ---- F1 MFMA: wave wv owns h-rows [wv*32, wv*32+32) ----
  f32x16 acc;
  #pragma unroll
  for (int e = 0; e < 16; ++e) acc[e] = 0.f;
  const int orow = wv * 32 + (lane & 31);
  const int bcol = lane & 31;
  const int kh8 = (lane >> 5) * 8;
  #pragma unroll
  for (int kc8 = 0; kc8 < 8; ++kc8) {        // 8 k-steps of 16
    int kfull = kc8 * 16 + kh8;
    bf16x8 a  = ldfrag_sw(Xh, orow, kfull);
    bf16x8 th = ldfrag_sw(Tfh, bcol, kfull);
    bf16x8 tl = ldfrag_sw(Tfl, bcol, kfull);
    acc = __builtin_amdgcn_mfma_f32_32x32x16_bf16(a, th, acc, 0, 0, 0);
    acc = __builtin_amdgcn_mfma_f32_32x32x16_bf16(a, tl, acc, 0, 0, 0);
  }
  __syncthreads();  // all frag reads of Xh done before aliasing it

  // ---- write A to transpose buffers Ar[n][h], Ai[n][h] (alias Xh region) ----
  float* Arp = (float*)Xh;          // [16][132]
  float* Aip = Arp + 16 * 132;      // [16][132]; total 16896 B <= 32768 B
  {
    const int col = lane & 31;
    #pragma unroll
    for (int r = 0; r < 16; ++r) {
      int h = wv * 32 + (r & 3) + 8 * (r >> 2) + 4 * (lane >> 5);
      if (col < 16) Arp[col * 132 + h] = acc[r];
      else          Aip[(col - 16) * 132 + h] = acc[r];
    }
  }
  __syncthreads();

  // ---- F2 (fp32): thread t -> (m = t>>4, n = t&15) ----
  {
    const int m = t >> 4, n = t & 15;
    const float* tc = tab + 8192 + m * 128;   // T2CT[m][h]
    const float* ts = tab + 10240 + m * 128;  // T2ST[m][h]
    const float* ar = Arp + n * 132;
    const float* ai = Aip + n * 132;
    float xr = 0.f, xi = 0.f;
    #pragma unroll 8
    for (int h4 = 0; h4 < 128; h4 += 4) {
      float4 av = *(const float4*)(ar + h4);
      float4 iv = *(const float4*)(ai + h4);
      float4 cv = *(const float4*)(tc + h4);
      float4 sv = *(const float4*)(ts + h4);
      xr += av.x * cv.x + iv.x * sv.x;  xi += iv.x * cv.x - av.x * sv.x;
      xr += av.y * cv.y + iv.y * sv.y;  xi += iv.y * cv.y - av.y * sv.y;
      xr += av.z * cv.z + iv.z * sv.z;  xi += iv.z * cv.z - av.z * sv.z;
      xr += av.w * cv.w + iv.w * sv.w;  xi += iv.w * cv.w - av.w * sv.w;
    }
    size_t base = ((size_t)(b * 128 + c)) * 512 + (size_t)(m * 16 + n) * 2;
    xtop[base] = xr; xtop[base + 1] = xi;
  }
}

// z[b,r] += partial over i-chunk; z zeroed by memset beforehand.
__global__ __launch_bounds__(256) void k_z(const float* __restrict__ xtop,
                                           const float* __restrict__ vre,
                                           const float* __restrict__ vim,
                                           float* __restrict__ zout) {
  int b = blockIdx.x, ic = blockIdx.y, t = threadIdx.x;
  float zr[8], zi[8];
  #pragma unroll
  for (int r = 0; r < 8; ++r) { zr[r] = 0.f; zi[r] = 0.f; }
  const float* xb = xtop + ((size_t)b * 128) * 512;
  for (int i = ic * 16; i < ic * 16 + 16; ++i) {
    float xr = xb[i * 512 + t * 2], xi = xb[i * 512 + t * 2 + 1];
    #pragma unroll
    for (int r = 0; r < 8; ++r) {
      float vr = vre[(size_t)(i * 8 + r) * 256 + t];
      float vi = vim[(size_t)(i * 8 + r) * 256 + t];
      zr[r] += xr * vr + xi * vi;
      zi[r] += xi * vr - xr * vi;
    }
  }
  #pragma unroll
  for (int r = 0; r < 8; ++r)
    for (int off = 32; off > 0; off >>= 1) {
      zr[r] += __shfl_down(zr[r], off);
      zi[r] += __shfl_down(zi[r], off);
    }
  __shared__ float red[4][16];
  int wid = t >> 6, lane = t & 63;
  if (lane == 0) {
    #pragma unroll
    for (int r = 0; r < 8; ++r) { red[wid][r * 2] = zr[r]; red[wid][r * 2 + 1] = zi[r]; }
  }
  __syncthreads();
  if (t < 16) atomicAdd(&zout[b * 16 + t], red[0][t] + red[1][t] + red[2][t] + red[3][t]);
}

// otop[b,o,mn] += partial over i-chunk (+ U z term from ic==0 chunk).
__global__ __launch_bounds__(256) void k_mix(const float* __restrict__ xtop,
                                             const float* __restrict__ wre,
                                             const float* __restrict__ wim,
                                             const float* __restrict__ ure,
                                             const float* __restrict__ uim,
                                             const float* __restrict__ z,
                                             float* __restrict__ otop) {
  int o0 = blockIdx.x * 4, b0 = blockIdx.y * 2, ic = blockIdx.z, t = threadIdx.x;
  float ar[2][4], ai[2][4];
  #pragma unroll
  for (int bb = 0; bb < 2; ++bb)
    #pragma unroll
    for (int oo = 0; oo < 4; ++oo) { ar[bb][oo] = 0.f; ai[bb][oo] = 0.f; }
  const float* x0 = xtop + ((size_t)(b0 * 128)) * 512;
  const float* x1 = x0 + 128 * 512;
  for (int i = ic * 16; i < ic * 16 + 16; ++i) {
    float x0r = x0[i * 512 + t * 2], x0i = x0[i * 512 + t * 2 + 1];
    float x1r = x1[i * 512 + t * 2], x1i = x1[i * 512 + t * 2 + 1];
    #pragma unroll
    for (int oo = 0; oo < 4; ++oo) {
      size_t di = (size_t)((o0 + oo) * 128 + i) * 256 + t;
      float dr = wre[di], dj = wim[di];
      ar[0][oo] += dr * x0r - dj * x0i; ai[0][oo] += dr * x0i + dj * x0r;
      ar[1][oo] += dr * x1r - dj * x1i; ai[1][oo] += dr * x1i + dj * x1r;
    }
  }
  if (ic == 0) {
    float zr[2][8], zi[2][8];
    #pragma unroll
    for (int bb = 0; bb < 2; ++bb)
      #pragma unroll
      for (int r = 0; r < 8; ++r) {
        zr[bb][r] = z[(b0 + bb) * 16 + r * 2];
        zi[bb][r] = z[(b0 + bb) * 16 + r * 2 + 1];
      }
    #pragma unroll
    for (int oo = 0; oo < 4; ++oo)
      #pragma unroll
      for (int r = 0; r < 8; ++r) {
        float urv = ure[(size_t)((o0 + oo) * 8 + r) * 256 + t];
        float uiv = uim[(size_t)((o0 + oo) * 8 + r) * 256 + t];
        #pragma unroll
        for (int bb = 0; bb < 2; ++bb) {
          ar[bb][oo] += urv * zr[bb][r] - uiv * zi[bb][r];
          ai[bb][oo] += urv * zi[bb][r] + uiv * zr[bb][r];
        }
      }
  }
  #pragma unroll
  for (int bb = 0; bb < 2; ++bb)
    #pragma unroll
    for (int oo = 0; oo < 4; ++oo) {
      size_t oi = ((size_t)((b0 + bb) * 128 + o0 + oo) * 256 + (size_t)t) * 2;
      atomicAdd(&otop[oi], ar[bb][oo]);
      atomicAdd(&otop[oi + 1], ai[bb][oo]);
    }
}

// Fused inverse-DFT + skip-GEMM + activation.
// Block = (h, b): output tile [128 o][128 w].
// ONLY change vs the round-4/6 verified version: skip_w A-frags come directly
// from the swf prep buffer (global, L2-hot) instead of LDS staging — drops
// Ah/Al (−18 KB LDS → 4 blocks/CU) and one global+split+write pass per chunk.
__global__ __launch_bounds__(256) void k_out(const float* __restrict__ x,
                                             const unsigned short* __restrict__ swf,
                                             const float* __restrict__ otop,
                                             const float* __restrict__ tab,
                                             float* __restrict__ out) {
  __shared__ unsigned short Ylds[128 * 36];  // [o][k]: k<16 Yr[n], k>=16 Yi[n]
  __shared__ unsigned short Tlds[128 * 36];  // [w][k]: k<16 I2C[w][n], k>=16 I2NS[w][n]
  __shared__ unsigned short Bh[128 * 36], Bl[128 * 36];  // x tile  [w][c_local]
  const int h = blockIdx.x, b = blockIdx.y;
  const int t = threadIdx.x;
  const int lane = t & 63, wv = t >> 6;
  const int kh8 = (lane >> 5) * 8;
  const int o_lane = wv * 32 + (lane & 31);

  // ---- build T' (bf16 I2 tables, concatenated cos|sin per w) ----
  {
    int w = t >> 1, half = t & 1;
    const float* src = tab + (half ? 14336 : 12288) + w * 16;
    #pragma unroll
    for (int q = 0; q < 4; ++q) {
      float4 v = *(const float4*)(src + q * 4);
      int k0 = half * 16 + q * 4;
      Tlds[w * 36 + k0 + 0] = bf_rnd(v.x);
      Tlds[w * 36 + k0 + 1] = bf_rnd(v.y);
      Tlds[w * 36 + k0 + 2] = bf_rnd(v.z);
      Tlds[w * 36 + k0 + 3] = bf_rnd(v.w);
    }
  }
  // ---- I1: Y[o][n] = sum_m X[o][m][n] e^{+2pi i m h/128} (fp32) ----
  {
    int o = t >> 1, nh = (t & 1) * 8;
    float yr[8], yi[8];
    #pragma unroll
    for (int j = 0; j < 8; ++j) { yr[j] = 0.f; yi[j] = 0.f; }
    const float* xb = otop + ((size_t)(b * 128 + o)) * 512 + nh * 2;
    #pragma unroll 4
    for (int m = 0; m < 16; ++m) {
      float cm = tab[4096 + h * 16 + m];   // uniform -> s_load
      float sm = tab[6144 + h * 16 + m];
      float4 q0 = *(const float4*)(xb + m * 32 + 0);
      float4 q1 = *(const float4*)(xb + m * 32 + 4);
      float4 q2 = *(const float4*)(xb + m * 32 + 8);
      float4 q3 = *(const float4*)(xb + m * 32 + 12);
      yr[0] += q0.x * cm - q0.y * sm; yi[0] += q0.x * sm + q0.y * cm;
      yr[1] += q0.z * cm - q0.w * sm; yi[1] += q0.z * sm + q0.w * cm;
      yr[2] += q1.x * cm - q1.y * sm; yi[2] += q1.x * sm + q1.y * cm;
      yr[3] += q1.z * cm - q1.w * sm; yi[3] += q1.z * sm + q1.w * cm;
      yr[4] += q2.x * cm - q2.y * sm; yi[4] += q2.x * sm + q2.y * cm;
      yr[5] += q2.z * cm - q2.w * sm; yi[5] += q2.z * sm + q2.w * cm;
      yr[6] += q3.x * cm - q3.y * sm; yi[6] += q3.x * sm + q3.y * cm;
      yr[7] += q3.z * cm - q3.w * sm; yi[7] += q3.z * sm + q3.w * cm;
    }
    #pragma unroll
    for (int j = 0; j < 8; ++j) {
      Ylds[o * 36 + nh + j] = bf_rnd(yr[j]);
      Ylds[o * 36 + 16 + nh + j] = bf_rnd(yi[j]);
    }
  }
  __syncthreads();

  f32x16 acc[4];
  #pragma unroll
  for (int nt = 0; nt < 4; ++nt)
    #pragma unroll
    for (int e = 0; e < 16; ++e) acc[nt][e] = 0.f;

  // ---- skip GEMM: C[o][w] = sum_c sw[o][c] x[b][c][h][w], K in 4 chunks ----
  for (int kc = 0; kc < 4; ++kc) {
    float xv[16];
    #pragma unroll
    for (int it = 0; it < 16; ++it) {
      int c = kc * 32 + it * 2 + (t >> 7);
      int w = t & 127;
      xv[it] = x[(size_t)(b * 128 + c) * 16384 + (size_t)h * 128 + w];
    }
    // A-frags direct from prep buffer (L2-hot; one contiguous 1 KB line/wave/table)
    bf16x8 ah[2], al[2];
    #pragma unroll
    for (int ks = 0; ks < 2; ++ks) {
      const unsigned short* base = swf + (size_t)((kc * 2 + ks) * 2) * 2048 + o_lane * 16 + kh8;
      ah[ks] = *(const bf16x8*)base;
      al[ks] = *(const bf16x8*)(base + 2048);
    }
    __syncthreads();  // previous chunk's frag reads complete
    #pragma unroll
    for (int it = 0; it < 16; ++it) {
      int cl = it * 2 + (t >> 7);
      int w = t & 127;
      unsigned short hb, lb;
      bf_split(xv[it], hb, lb);
      Bh[w * 36 + cl] = hb; Bl[w * 36 + cl] = lb;
    }
    __syncthreads();
    #pragma unroll
    for (int ks = 0; ks < 2; ++ks) {
      const int kb = ks * 16 + kh8;
      #pragma unroll
      for (int nt = 0; nt < 4; ++nt) {
        bf16x8 bh_ = ldfrag(&Bh[(nt * 32 + (lane & 31)) * 36 + kb]);
        bf16x8 bl_ = ldfrag(&Bl[(nt * 32 + (lane & 31)) * 36 + kb]);
        acc[nt] = __builtin_amdgcn_mfma_f32_32x32x16_bf16(ah[ks], bh_, acc[nt], 0, 0, 0);
        acc[nt] = __builtin_amdgcn_mfma_f32_32x32x16_bf16(ah[ks], bl_, acc[nt], 0, 0, 0);
        acc[nt] = __builtin_amdgcn_mfma_f32_32x32x16_bf16(al[ks], bh_, acc[nt], 0, 0, 0);
      }
    }
  }

  // ---- S2: spectral I2 via MFMA into the same accumulators ----
  #pragma unroll
  for (int ks = 0; ks < 2; ++ks) {
    const int kb = ks * 16 + kh8;
    bf16x8 ya = ldfrag(&Ylds[o_lane * 36 + kb]);
    #pragma unroll
    for (int nt = 0; nt < 4; ++nt) {
      bf16x8 tb = ldfrag(&Tlds[(nt * 32 + (lane & 31)) * 36 + kb]);
      acc[nt] = __builtin_amdgcn_mfma_f32_32x32x16_bf16(ya, tb, acc[nt], 0, 0, 0);
    }
  }

  // ---- epilogue: activation + store ----
  #pragma unroll
  for (int nt = 0; nt < 4; ++nt) {
    int w = nt * 32 + (lane & 31);
    #pragma unroll
    for (int r = 0; r < 16; ++r) {
      int o = wv * 32 + (r & 3) + 8 * (r >> 2) + 4 * (lane >> 5);
      float v = acc[nt][r];
      out[((size_t)(b * 128 + o)) * 16384 + (size_t)h * 128 + w] = v * __expf(-v * v);
    }
  }
}

extern "C" void kernel_launch(void* const* d_in, const int* in_sizes, int n_in,
                              void* d_out, int out_size, void* d_ws, size_t ws_size,
                              hipStream_t stream) {
  const float* x  = (const float*)d_in[0];
  const float* wr = (const float*)d_in[1];
  const float* wi = (const float*)d_in[2];
  const float* ur = (const float*)d_in[3];
  const float* ui = (const float*)d_in[4];
  const float* vr = (const float*)d_in[5];
  const float* vi = (const float*)d_in[6];
  const float* sw = (const float*)d_in[7];
  float* out  = (float*)d_out;
  float* ws   = (float*)d_ws;
  float* tab  = ws + TAB_OFF;
  float* xtop = ws + XTOP_OFF;
  float* z    = ws + Z_OFF;
  float* otop = ws + OTOP_OFF;
  unsigned short* tf  = (unsigned short*)(ws + TF_OFF);
  unsigned short* swf = (unsigned short*)(ws + SWF_OFF);  // aliases xtop (dead after k_mix)

  hipMemsetAsync(z, 0, 256 * sizeof(float), stream);
  hipMemsetAsync(otop, 0, 1048576 * sizeof(float), stream);
  hipLaunchKernelGGL(k_tab, dim3(64), dim3(256), 0, stream, tab);
  hipLaunchKernelGGL(k_fprep, dim3(16), dim3(256), 0, stream, tf);
  hipLaunchKernelGGL(k_fwd, dim3(128, 16), dim3(256), 0, stream, x, tf, tab, xtop);
  hipLaunchKernelGGL(k_z,   dim3(16, 8), dim3(256), 0, stream, xtop, vr, vi, z);
  hipLaunchKernelGGL(k_mix, dim3(32, 8, 8), dim3(256), 0, stream, xtop, wr, wi, ur, ui, z, otop);
  hipLaunchKernelGGL(k_wprep, dim3(64), dim3(256), 0, stream, sw, swf);  // after k_mix: xtop is dead
  hipLaunchKernelGGL(k_out, dim3(128, 16), dim3(256), 0, stream, x, swf, otop, tab, out);
}